// Round 2
// baseline (2529.522 us; speedup 1.0000x reference)
//
#include <hip/hip_runtime.h>
#include <hip/hip_bf16.h>

typedef __attribute__((ext_vector_type(8))) short short8;
typedef __attribute__((ext_vector_type(4))) float f32x4;
using bf16 = __hip_bfloat16;

constexpr int C  = 256;
constexpr int BB = 8;
constexpr int NN = 2048;

#define DEVI __device__ __forceinline__

DEVI short8 ldg8(const bf16* p) { return *reinterpret_cast<const short8*>(p); }

DEVI f32x4 mfma16(short8 a, short8 b, f32x4 c) {
  return __builtin_amdgcn_mfma_f32_16x16x32_bf16(a, b, c, 0, 0, 0);
}

DEVI void split2(float x, bf16& h, bf16& l) {
  h = __float2bfloat16(x);
  l = __float2bfloat16(x - __bfloat162float(h));
}

// ---------------- weight fp32 -> bf16 hi/lo ----------------
__global__ __launch_bounds__(256) void k_cvt(const float* __restrict__ s,
                                             bf16* __restrict__ dh,
                                             bf16* __restrict__ dl, int n) {
  int i = blockIdx.x * 256 + threadIdx.x;
  int st = gridDim.x * 256;
  for (; i < n; i += st) {
    bf16 h, l;
    split2(s[i], h, l);
    dh[i] = h; dl[i] = l;
  }
}

// ---------------- x [B][C][N] f32 -> Xt hi/lo [B][N][C] ----------------
__global__ __launch_bounds__(256) void k_tin(const float* __restrict__ x,
                                             bf16* __restrict__ Xh,
                                             bf16* __restrict__ Xl) {
  __shared__ float tile[64][65];
  int b = blockIdx.z, n0 = blockIdx.x * 64, c0 = blockIdx.y * 64;
  int tn = threadIdx.x & 63, tq = threadIdx.x >> 6;
#pragma unroll
  for (int i = 0; i < 16; ++i) {
    int cc = i * 4 + tq;
    tile[cc][tn] = x[((size_t)(b * C + c0 + cc)) * NN + n0 + tn];
  }
  __syncthreads();
#pragma unroll
  for (int i = 0; i < 16; ++i) {
    int nn2 = i * 4 + tq;
    size_t idx = ((size_t)(b * NN + n0 + nn2)) * C + c0 + tn;
    bf16 h, l;
    split2(tile[tn][nn2], h, l);
    Xh[idx] = h; Xl[idx] = l;
  }
}

// ---------------- split GEMM: Out[b][n][o] = sum_k A[b][n][k] W[o][k] (+bias[o]) ----
// 3-term: Ah*Wh + Ah*Wl + Al*Wh
template <bool OUTF32, bool BIASJ, bool STATS>
__global__ __launch_bounds__(256) void k_gemm_tr(const bf16* __restrict__ Ah,
                                                 const bf16* __restrict__ Al,
                                                 const bf16* __restrict__ Wh,
                                                 const bf16* __restrict__ Wl,
                                                 const float* __restrict__ bias,
                                                 float* __restrict__ OutF,
                                                 bf16* __restrict__ Oh,
                                                 bf16* __restrict__ Ol, int OD,
                                                 float* __restrict__ sS,
                                                 float* __restrict__ sS2) {
  __shared__ float smS[64], smS2[64];
  int b = blockIdx.z, i0 = blockIdx.x * 64, j0 = blockIdx.y * 64;
  int t = threadIdx.x, lane = t & 63, w = t >> 6;
  int l15 = lane & 15, l4 = lane >> 4;
  if (STATS) {
    if (t < 64) { smS[t] = 0.f; smS2[t] = 0.f; }
    __syncthreads();
  }
  size_t arow = ((size_t)(b * NN + i0 + w * 16 + l15)) * C + l4 * 8;
  short8 ah[8], al[8];
#pragma unroll
  for (int ks = 0; ks < 8; ++ks) {
    ah[ks] = ldg8(Ah + arow + ks * 32);
    al[ks] = ldg8(Al + arow + ks * 32);
  }
#pragma unroll
  for (int ct = 0; ct < 4; ++ct) {
    size_t wrow = (size_t)(j0 + ct * 16 + l15) * C + l4 * 8;
    f32x4 acc = {0.f, 0.f, 0.f, 0.f};
#pragma unroll
    for (int ks = 0; ks < 8; ++ks) {
      short8 wh = ldg8(Wh + wrow + ks * 32);
      short8 wl = ldg8(Wl + wrow + ks * 32);
      acc = mfma16(ah[ks], wh, acc);
      acc = mfma16(ah[ks], wl, acc);
      acc = mfma16(al[ks], wh, acc);
    }
    float bj = 0.f;
    if (BIASJ) bj = bias[j0 + ct * 16 + l15];
    float s = 0.f, s2 = 0.f;
#pragma unroll
    for (int r = 0; r < 4; ++r) {
      float v = acc[r] + bj;
      int row = i0 + w * 16 + l4 * 4 + r;
      size_t idx = ((size_t)(b * NN + row)) * OD + j0 + ct * 16 + l15;
      if (OUTF32) {
        OutF[idx] = v;
      } else {
        bf16 h, l;
        split2(v, h, l);
        Oh[idx] = h; Ol[idx] = l;
      }
      if (STATS) { s += v; s2 += v * v; }
    }
    if (STATS) {
      s += __shfl_xor(s, 16); s2 += __shfl_xor(s2, 16);
      s += __shfl_xor(s, 32); s2 += __shfl_xor(s2, 32);
      if (l4 == 0) {
        atomicAdd(&smS[ct * 16 + l15], s);
        atomicAdd(&smS2[ct * 16 + l15], s2);
      }
    }
  }
  if (STATS) {
    __syncthreads();
    if (t < 64) {
      atomicAdd(&sS[j0 + t], smS[t]);
      atomicAdd(&sS2[j0 + t], smS2[t]);
    }
  }
}

// ---------------- split GEMM: V[b][c][m] = sum_k W[c][k] Xt[b][m][k] + bias[c] ------
__global__ __launch_bounds__(256) void k_gemm_nm(const bf16* __restrict__ Wh,
                                                 const bf16* __restrict__ Wl,
                                                 const bf16* __restrict__ Xh,
                                                 const bf16* __restrict__ Xl,
                                                 const float* __restrict__ bias,
                                                 bf16* __restrict__ Vh,
                                                 bf16* __restrict__ Vl) {
  int b = blockIdx.z, i0 = blockIdx.x * 64, j0 = blockIdx.y * 64;
  int t = threadIdx.x, lane = t & 63, w = t >> 6;
  int l15 = lane & 15, l4 = lane >> 4;
  size_t wrow = (size_t)(i0 + w * 16 + l15) * C + l4 * 8;
  short8 ah[8], al[8];
#pragma unroll
  for (int ks = 0; ks < 8; ++ks) {
    ah[ks] = ldg8(Wh + wrow + ks * 32);
    al[ks] = ldg8(Wl + wrow + ks * 32);
  }
#pragma unroll
  for (int ct = 0; ct < 4; ++ct) {
    size_t xrow = ((size_t)(b * NN + j0 + ct * 16 + l15)) * C + l4 * 8;
    f32x4 acc = {0.f, 0.f, 0.f, 0.f};
#pragma unroll
    for (int ks = 0; ks < 8; ++ks) {
      short8 xh = ldg8(Xh + xrow + ks * 32);
      short8 xl = ldg8(Xl + xrow + ks * 32);
      acc = mfma16(ah[ks], xh, acc);
      acc = mfma16(ah[ks], xl, acc);
      acc = mfma16(al[ks], xh, acc);
    }
#pragma unroll
    for (int r = 0; r < 4; ++r) {
      int row = i0 + w * 16 + l4 * 4 + r;
      float v = acc[r] + bias[row];
      size_t idx = ((size_t)(b * C + row)) * NN + j0 + ct * 16 + l15;
      bf16 h, l;
      split2(v, h, l);
      Vh[idx] = h; Vl[idx] = l;
    }
  }
}

// ---------------- row softmax stats over E = Q Q^T (split 3-term) ----------------
__global__ __launch_bounds__(256) void k_rowstats(const bf16* __restrict__ Qh,
                                                  const bf16* __restrict__ Ql,
                                                  float* __restrict__ rm,
                                                  float* __restrict__ irs) {
  int b = blockIdx.y;
  int t = threadIdx.x, lane = t & 63, w = t >> 6;
  int l15 = lane & 15, l4 = lane >> 4;
  int m0 = blockIdx.x * 64 + w * 16;
  size_t qrow = ((size_t)(b * NN + m0 + l15)) * 64 + l4 * 8;
  short8 ah0 = ldg8(Qh + qrow), ah1 = ldg8(Qh + qrow + 32);
  short8 al0 = ldg8(Ql + qrow), al1 = ldg8(Ql + qrow + 32);
  float lmax[4], lsum[4];
#pragma unroll
  for (int r = 0; r < 4; ++r) { lmax[r] = -3.4e38f; lsum[r] = 0.f; }
  for (int nb = 0; nb < NN / 16; ++nb) {
    size_t brow = ((size_t)(b * NN + nb * 16 + l15)) * 64 + l4 * 8;
    short8 bh0 = ldg8(Qh + brow), bh1 = ldg8(Qh + brow + 32);
    short8 bl0 = ldg8(Ql + brow), bl1 = ldg8(Ql + brow + 32);
    f32x4 e = {0.f, 0.f, 0.f, 0.f};
    e = mfma16(ah0, bh0, e); e = mfma16(ah1, bh1, e);
    e = mfma16(ah0, bl0, e); e = mfma16(ah1, bl1, e);
    e = mfma16(al0, bh0, e); e = mfma16(al1, bh1, e);
#pragma unroll
    for (int r = 0; r < 4; ++r) {
      float v = e[r];
      float nm = fmaxf(lmax[r], v);
      lsum[r] = lsum[r] * __expf(lmax[r] - nm) + __expf(v - nm);
      lmax[r] = nm;
    }
  }
#pragma unroll
  for (int r = 0; r < 4; ++r) {
    for (int mk = 1; mk < 16; mk <<= 1) {
      float om = __shfl_xor(lmax[r], mk, 16);
      float os = __shfl_xor(lsum[r], mk, 16);
      float nm = fmaxf(lmax[r], om);
      lsum[r] = lsum[r] * __expf(lmax[r] - nm) + os * __expf(om - nm);
      lmax[r] = nm;
    }
  }
  if (l15 == 0) {
#pragma unroll
    for (int r = 0; r < 4; ++r) {
      int m = m0 + l4 * 4 + r;
      rm[b * NN + m] = lmax[r];
      irs[b * NN + m] = 1.0f / lsum[r];
    }
  }
}

// ---------------- fused attention apply: D = X - (V att)/(1e-9+colsum) ----------
__global__ __launch_bounds__(256) void k_attnY(const bf16* __restrict__ Qh,
                                               const bf16* __restrict__ Ql,
                                               const bf16* __restrict__ Vh,
                                               const bf16* __restrict__ Vl,
                                               const float* __restrict__ rm,
                                               const float* __restrict__ irs,
                                               const float* __restrict__ Xf,
                                               bf16* __restrict__ Dh,
                                               bf16* __restrict__ Dl) {
  __shared__ alignas(16) bf16 smPh[4][16][40];
  __shared__ alignas(16) bf16 smPl[4][16][40];
  int b = blockIdx.y;
  int t = threadIdx.x, lane = t & 63, w = t >> 6;
  int l15 = lane & 15, l4 = lane >> 4;
  int n0 = blockIdx.x * 64 + w * 16;
  size_t qrow = ((size_t)(b * NN + n0 + l15)) * 64 + l4 * 8;
  short8 qh0 = ldg8(Qh + qrow), qh1 = ldg8(Qh + qrow + 32);
  short8 ql0 = ldg8(Ql + qrow), ql1 = ldg8(Ql + qrow + 32);
  f32x4 zero = {0.f, 0.f, 0.f, 0.f};
  f32x4 acc[16];
#pragma unroll
  for (int ct = 0; ct < 16; ++ct) acc[ct] = zero;
  f32x4 cac = zero;
  for (int mb = 0; mb < NN / 32; ++mb) {
    int m0 = mb * 32;
#pragma unroll
    for (int sub = 0; sub < 2; ++sub) {
      int ms = m0 + sub * 16;
      size_t brow = ((size_t)(b * NN + ms + l15)) * 64 + l4 * 8;
      short8 bh0 = ldg8(Qh + brow), bh1 = ldg8(Qh + brow + 32);
      short8 bl0 = ldg8(Ql + brow), bl1 = ldg8(Ql + brow + 32);
      f32x4 e = zero;
      e = mfma16(qh0, bh0, e); e = mfma16(qh1, bh1, e);
      e = mfma16(qh0, bl0, e); e = mfma16(qh1, bl1, e);
      e = mfma16(ql0, bh0, e); e = mfma16(ql1, bh1, e);
      float rmv = rm[b * NN + ms + l15];
      float iv = irs[b * NN + ms + l15];
#pragma unroll
      for (int r = 0; r < 4; ++r) {
        float p = __expf(e[r] - rmv) * iv;
        cac[r] += p;
        bf16 ph, pl;
        split2(p, ph, pl);
        smPh[w][l4 * 4 + r][sub * 16 + l15] = ph;
        smPl[w][l4 * 4 + r][sub * 16 + l15] = pl;
      }
    }
    asm volatile("s_waitcnt lgkmcnt(0)" ::: "memory");
    __builtin_amdgcn_sched_barrier(0);
    short8 pah = *reinterpret_cast<const short8*>(&smPh[w][l15][l4 * 8]);
    short8 pal = *reinterpret_cast<const short8*>(&smPl[w][l15][l4 * 8]);
#pragma unroll
    for (int ct = 0; ct < 16; ++ct) {
      size_t vrow = ((size_t)(b * C + ct * 16 + l15)) * NN + m0 + l4 * 8;
      short8 vh = ldg8(Vh + vrow);
      short8 vl = ldg8(Vl + vrow);
      acc[ct] = mfma16(pah, vh, acc[ct]);
      acc[ct] = mfma16(pah, vl, acc[ct]);
      acc[ct] = mfma16(pal, vh, acc[ct]);
    }
  }
#pragma unroll
  for (int r = 0; r < 4; ++r) {
    for (int mk = 1; mk < 16; mk <<= 1) cac[r] += __shfl_xor(cac[r], mk, 16);
  }
  float inv[4];
#pragma unroll
  for (int r = 0; r < 4; ++r) inv[r] = 1.0f / (1e-9f + cac[r]);
#pragma unroll
  for (int ct = 0; ct < 16; ++ct) {
#pragma unroll
    for (int r = 0; r < 4; ++r) {
      int n = n0 + l4 * 4 + r;
      int c = ct * 16 + l15;
      size_t idx = ((size_t)(b * NN + n)) * C + c;
      float d = Xf[idx] - acc[ct][r] * inv[r];
      bf16 h, l;
      split2(d, h, l);
      Dh[idx] = h; Dl[idx] = l;
    }
  }
}

// ---------------- BN finish ----------------
__global__ void k_bnfin(const float* __restrict__ sS, const float* __restrict__ sS2,
                        const float* __restrict__ g, const float* __restrict__ bb,
                        float* __restrict__ scale, float* __restrict__ shift) {
  int c = threadIdx.x;
  float cnt = (float)(BB * NN);
  float mean = sS[c] / cnt;
  float var = fmaxf(sS2[c] / cnt - mean * mean, 0.f);
  float sc = g[c] * rsqrtf(var + 1e-5f);
  scale[c] = sc;
  shift[c] = bb[c] - mean * sc;
}

// ---------------- BN + ReLU (+ residual + out write) ----------------
template <bool RES>
__global__ __launch_bounds__(256) void k_bnrelu(const float* __restrict__ Tt,
                                                const float* __restrict__ scale,
                                                const float* __restrict__ shift,
                                                float* __restrict__ Xf,
                                                bf16* __restrict__ Xh,
                                                bf16* __restrict__ Xl,
                                                float* __restrict__ outp, int Loff) {
  int row = blockIdx.x;  // b*NN + n
  int c = threadIdx.x;
  size_t idx = (size_t)row * C + c;
  float v = Tt[idx] * scale[c] + shift[c];
  v = fmaxf(v, 0.f);
  if (RES) v += Xf[idx];
  Xf[idx] = v;
  bf16 h, l;
  split2(v, h, l);
  Xh[idx] = h; Xl[idx] = l;
  if (RES) {
    int b = row >> 11;
    int n = row & (NN - 1);
    outp[((size_t)(b * 1024 + Loff + c)) * NN + n] = v;
  }
}

extern "C" void kernel_launch(void* const* d_in, const int* in_sizes, int n_in,
                              void* d_out, int out_size, void* d_ws, size_t ws_size,
                              hipStream_t stream) {
  const float* x       = (const float*)d_in[0];
  const float* conv1_w = (const float*)d_in[1];
  const float* conv2_w = (const float*)d_in[2];
  const float* bn1_g   = (const float*)d_in[3];
  const float* bn1_b   = (const float*)d_in[4];
  const float* bn2_g   = (const float*)d_in[5];
  const float* bn2_b   = (const float*)d_in[6];
  const float* wqk     = (const float*)d_in[7];
  const float* wv      = (const float*)d_in[8];
  const float* bv      = (const float*)d_in[9];
  const float* wt      = (const float*)d_in[10];
  const float* bt      = (const float*)d_in[11];
  const float* sg      = (const float*)d_in[12];
  const float* sb      = (const float*)d_in[13];
  float* out = (float*)d_out;

  char* p = (char*)d_ws;
  auto take = [&](size_t n) { char* r = p; p += n; return r; };
  bf16* WB1h = (bf16*)take(131072);
  bf16* WB1l = (bf16*)take(131072);
  bf16* WB2h = (bf16*)take(131072);
  bf16* WB2l = (bf16*)take(131072);
  bf16* WBQh = (bf16*)take(131072);
  bf16* WBQl = (bf16*)take(131072);
  bf16* WBVh = (bf16*)take(524288);
  bf16* WBVl = (bf16*)take(524288);
  bf16* WBTh = (bf16*)take(524288);
  bf16* WBTl = (bf16*)take(524288);
  bf16* XTh  = (bf16*)take(8388608);
  bf16* XTl  = (bf16*)take(8388608);
  float* XF  = (float*)take(16777216);
  bf16* QTh  = (bf16*)take(2097152);
  bf16* QTl  = (bf16*)take(2097152);
  bf16* VBh  = (bf16*)take(8388608);
  bf16* VBl  = (bf16*)take(8388608);
  float* TT  = (float*)VBh;  // alias: t-GEMM runs after attnY consumed V
  bf16* DTh  = (bf16*)take(8388608);
  bf16* DTl  = (bf16*)take(8388608);
  float* RM   = (float*)take(65536);
  float* IRS  = (float*)take(65536);
  float* STAT = (float*)take(12288);
  float* SCSH = (float*)take(12288);

  hipMemsetAsync(STAT, 0, 6 * 512 * sizeof(float), stream);
  k_cvt<<<256, 256, 0, stream>>>(conv1_w, WB1h, WB1l, 65536);
  k_cvt<<<256, 256, 0, stream>>>(conv2_w, WB2h, WB2l, 65536);
  k_cvt<<<256, 256, 0, stream>>>(wqk, WBQh, WBQl, 65536);
  k_cvt<<<1024, 256, 0, stream>>>(wv, WBVh, WBVl, 262144);
  k_cvt<<<1024, 256, 0, stream>>>(wt, WBTh, WBTl, 262144);
  k_tin<<<dim3(32, 4, 8), 256, 0, stream>>>(x, XTh, XTl);

  // conv1 + bn1 + relu   (note: TT aliases VB, safe — V not yet used)
  k_gemm_tr<true, false, true><<<dim3(32, 4, 8), 256, 0, stream>>>(
      XTh, XTl, WB1h, WB1l, nullptr, TT, nullptr, nullptr, 256, STAT + 0, STAT + 256);
  k_bnfin<<<1, 256, 0, stream>>>(STAT + 0, STAT + 256, bn1_g, bn1_b, SCSH + 0, SCSH + 256);
  k_bnrelu<false><<<16384, 256, 0, stream>>>(TT, SCSH + 0, SCSH + 256, XF, XTh, XTl, nullptr, 0);

  // conv2 + bn2 + relu
  k_gemm_tr<true, false, true><<<dim3(32, 4, 8), 256, 0, stream>>>(
      XTh, XTl, WB2h, WB2l, nullptr, TT, nullptr, nullptr, 256, STAT + 512, STAT + 768);
  k_bnfin<<<1, 256, 0, stream>>>(STAT + 512, STAT + 768, bn2_g, bn2_b, SCSH + 512, SCSH + 768);
  k_bnrelu<false><<<16384, 256, 0, stream>>>(TT, SCSH + 512, SCSH + 768, XF, XTh, XTl, nullptr, 0);

  for (int L = 0; L < 4; ++L) {
    float* ST = STAT + (2 + L) * 512;
    float* SC = SCSH + (2 + L) * 512;
    // q projection -> Qt hi/lo [B][N][64]
    k_gemm_tr<false, false, false><<<dim3(32, 1, 8), 256, 0, stream>>>(
        XTh, XTl, WBQh + L * 16384, WBQl + L * 16384, nullptr, nullptr, QTh, QTl, 64,
        nullptr, nullptr);
    // v projection -> V hi/lo [B][C][N]
    k_gemm_nm<<<dim3(4, 32, 8), 256, 0, stream>>>(WBVh + L * 65536, WBVl + L * 65536,
                                                  XTh, XTl, bv + L * 256, VBh, VBl);
    // softmax row stats
    k_rowstats<<<dim3(32, 8), 256, 0, stream>>>(QTh, QTl, RM, IRS);
    // fused E-recompute + renorm + V-apply + subtract -> D hi/lo
    k_attnY<<<dim3(32, 8), 256, 0, stream>>>(QTh, QTl, VBh, VBl, RM, IRS, XF, DTh, DTl);
    // t projection + stats (TT aliases VB — V fully consumed by attnY above)
    k_gemm_tr<true, true, true><<<dim3(32, 4, 8), 256, 0, stream>>>(
        DTh, DTl, WBTh + L * 65536, WBTl + L * 65536, bt + L * 256, TT, nullptr, nullptr,
        256, ST, ST + 256);
    k_bnfin<<<1, 256, 0, stream>>>(ST, ST + 256, sg + L * 256, sb + L * 256, SC, SC + 256);
    // bn + relu + residual + output slice
    k_bnrelu<true><<<16384, 256, 0, stream>>>(TT, SC, SC + 256, XF, XTh, XTl, out, L * 256);
  }
}

// Round 3
// 2328.896 us; speedup vs baseline: 1.0861x; 1.0861x over previous
//
#include <hip/hip_runtime.h>
#include <hip/hip_bf16.h>

typedef __attribute__((ext_vector_type(8))) short short8;
typedef __attribute__((ext_vector_type(4))) float f32x4;
using bf16 = __hip_bfloat16;

constexpr int C  = 256;
constexpr int BB = 8;
constexpr int NN = 2048;

#define DEVI __device__ __forceinline__

DEVI short8 ldg8(const bf16* p) { return *reinterpret_cast<const short8*>(p); }

DEVI f32x4 mfma16(short8 a, short8 b, f32x4 c) {
  return __builtin_amdgcn_mfma_f32_16x16x32_bf16(a, b, c, 0, 0, 0);
}

DEVI void split2(float x, bf16& h, bf16& l) {
  h = __float2bfloat16(x);
  l = __float2bfloat16(x - __bfloat162float(h));
}

// ---------------- weight fp32 -> bf16 hi/lo ----------------
__global__ __launch_bounds__(256) void k_cvt(const float* __restrict__ s,
                                             bf16* __restrict__ dh,
                                             bf16* __restrict__ dl, int n) {
  int i = blockIdx.x * 256 + threadIdx.x;
  int st = gridDim.x * 256;
  for (; i < n; i += st) {
    bf16 h, l;
    split2(s[i], h, l);
    dh[i] = h; dl[i] = l;
  }
}

// ---------------- x [B][C][N] f32 -> Xt hi/lo [B][N][C] ----------------
__global__ __launch_bounds__(256) void k_tin(const float* __restrict__ x,
                                             bf16* __restrict__ Xh,
                                             bf16* __restrict__ Xl) {
  __shared__ float tile[64][65];
  int b = blockIdx.z, n0 = blockIdx.x * 64, c0 = blockIdx.y * 64;
  int tn = threadIdx.x & 63, tq = threadIdx.x >> 6;
#pragma unroll
  for (int i = 0; i < 16; ++i) {
    int cc = i * 4 + tq;
    tile[cc][tn] = x[((size_t)(b * C + c0 + cc)) * NN + n0 + tn];
  }
  __syncthreads();
#pragma unroll
  for (int i = 0; i < 16; ++i) {
    int nn2 = i * 4 + tq;
    size_t idx = ((size_t)(b * NN + n0 + nn2)) * C + c0 + tn;
    bf16 h, l;
    split2(tile[tn][nn2], h, l);
    Xh[idx] = h; Xl[idx] = l;
  }
}

// ---------------- split GEMM: Out[b][n][o] = sum_k A[b][n][k] W[o][k] (+bias[o]) ----
template <bool OUTF32, bool BIASJ, bool STATS>
__global__ __launch_bounds__(256) void k_gemm_tr(const bf16* __restrict__ Ah,
                                                 const bf16* __restrict__ Al,
                                                 const bf16* __restrict__ Wh,
                                                 const bf16* __restrict__ Wl,
                                                 const float* __restrict__ bias,
                                                 float* __restrict__ OutF,
                                                 bf16* __restrict__ Oh,
                                                 bf16* __restrict__ Ol, int OD,
                                                 float* __restrict__ sS,
                                                 float* __restrict__ sS2) {
  __shared__ float smS[64], smS2[64];
  int b = blockIdx.z, i0 = blockIdx.x * 64, j0 = blockIdx.y * 64;
  int t = threadIdx.x, lane = t & 63, w = t >> 6;
  int l15 = lane & 15, l4 = lane >> 4;
  if (STATS) {
    if (t < 64) { smS[t] = 0.f; smS2[t] = 0.f; }
    __syncthreads();
  }
  size_t arow = ((size_t)(b * NN + i0 + w * 16 + l15)) * C + l4 * 8;
  short8 ah[8], al[8];
#pragma unroll
  for (int ks = 0; ks < 8; ++ks) {
    ah[ks] = ldg8(Ah + arow + ks * 32);
    al[ks] = ldg8(Al + arow + ks * 32);
  }
#pragma unroll
  for (int ct = 0; ct < 4; ++ct) {
    size_t wrow = (size_t)(j0 + ct * 16 + l15) * C + l4 * 8;
    f32x4 acc = {0.f, 0.f, 0.f, 0.f};
#pragma unroll
    for (int ks = 0; ks < 8; ++ks) {
      short8 wh = ldg8(Wh + wrow + ks * 32);
      short8 wl = ldg8(Wl + wrow + ks * 32);
      acc = mfma16(ah[ks], wh, acc);
      acc = mfma16(ah[ks], wl, acc);
      acc = mfma16(al[ks], wh, acc);
    }
    float bj = 0.f;
    if (BIASJ) bj = bias[j0 + ct * 16 + l15];
    float s = 0.f, s2 = 0.f;
#pragma unroll
    for (int r = 0; r < 4; ++r) {
      float v = acc[r] + bj;
      int row = i0 + w * 16 + l4 * 4 + r;
      size_t idx = ((size_t)(b * NN + row)) * OD + j0 + ct * 16 + l15;
      if (OUTF32) {
        OutF[idx] = v;
      } else {
        bf16 h, l;
        split2(v, h, l);
        Oh[idx] = h; Ol[idx] = l;
      }
      if (STATS) { s += v; s2 += v * v; }
    }
    if (STATS) {
      s += __shfl_xor(s, 16); s2 += __shfl_xor(s2, 16);
      s += __shfl_xor(s, 32); s2 += __shfl_xor(s2, 32);
      if (l4 == 0) {
        atomicAdd(&smS[ct * 16 + l15], s);
        atomicAdd(&smS2[ct * 16 + l15], s2);
      }
    }
  }
  if (STATS) {
    __syncthreads();
    if (t < 64) {
      atomicAdd(&sS[j0 + t], smS[t]);
      atomicAdd(&sS2[j0 + t], smS2[t]);
    }
  }
}

// ---------------- split GEMM: V[b][c][m] = sum_k W[c][k] Xt[b][m][k] + bias[c] ------
__global__ __launch_bounds__(256) void k_gemm_nm(const bf16* __restrict__ Wh,
                                                 const bf16* __restrict__ Wl,
                                                 const bf16* __restrict__ Xh,
                                                 const bf16* __restrict__ Xl,
                                                 const float* __restrict__ bias,
                                                 bf16* __restrict__ Vh,
                                                 bf16* __restrict__ Vl) {
  int b = blockIdx.z, i0 = blockIdx.x * 64, j0 = blockIdx.y * 64;
  int t = threadIdx.x, lane = t & 63, w = t >> 6;
  int l15 = lane & 15, l4 = lane >> 4;
  size_t wrow = (size_t)(i0 + w * 16 + l15) * C + l4 * 8;
  short8 ah[8], al[8];
#pragma unroll
  for (int ks = 0; ks < 8; ++ks) {
    ah[ks] = ldg8(Wh + wrow + ks * 32);
    al[ks] = ldg8(Wl + wrow + ks * 32);
  }
#pragma unroll
  for (int ct = 0; ct < 4; ++ct) {
    size_t xrow = ((size_t)(b * NN + j0 + ct * 16 + l15)) * C + l4 * 8;
    f32x4 acc = {0.f, 0.f, 0.f, 0.f};
#pragma unroll
    for (int ks = 0; ks < 8; ++ks) {
      short8 xh = ldg8(Xh + xrow + ks * 32);
      short8 xl = ldg8(Xl + xrow + ks * 32);
      acc = mfma16(ah[ks], xh, acc);
      acc = mfma16(ah[ks], xl, acc);
      acc = mfma16(al[ks], xh, acc);
    }
#pragma unroll
    for (int r = 0; r < 4; ++r) {
      int row = i0 + w * 16 + l4 * 4 + r;
      float v = acc[r] + bias[row];
      size_t idx = ((size_t)(b * C + row)) * NN + j0 + ct * 16 + l15;
      bf16 h, l;
      split2(v, h, l);
      Vh[idx] = h; Vl[idx] = l;
    }
  }
}

// ---------------- row softmax stats over E = Q Q^T (split 3-term) ----------------
// Block: 16 stat-rows; 4 waves each cover 512 of the n (softmax) axis.
__global__ __launch_bounds__(256) void k_rowstats(const bf16* __restrict__ Qh,
                                                  const bf16* __restrict__ Ql,
                                                  float* __restrict__ rm,
                                                  float* __restrict__ irs) {
  __shared__ float redM[4][16], redS[4][16];
  int b = blockIdx.y;
  int t = threadIdx.x, lane = t & 63, w = t >> 6;
  int l15 = lane & 15, l4 = lane >> 4;
  int m0 = blockIdx.x * 16;
  size_t qrow = ((size_t)(b * NN + m0 + l15)) * 64 + l4 * 8;
  short8 ah0 = ldg8(Qh + qrow), ah1 = ldg8(Qh + qrow + 32);
  short8 al0 = ldg8(Ql + qrow), al1 = ldg8(Ql + qrow + 32);
  float lmax[4], lsum[4];
#pragma unroll
  for (int r = 0; r < 4; ++r) { lmax[r] = -3.4e38f; lsum[r] = 0.f; }
  for (int nb = w * 32; nb < w * 32 + 32; ++nb) {
    size_t brow = ((size_t)(b * NN + nb * 16 + l15)) * 64 + l4 * 8;
    short8 bh0 = ldg8(Qh + brow), bh1 = ldg8(Qh + brow + 32);
    short8 bl0 = ldg8(Ql + brow), bl1 = ldg8(Ql + brow + 32);
    f32x4 e = {0.f, 0.f, 0.f, 0.f};
    e = mfma16(ah0, bh0, e); e = mfma16(ah1, bh1, e);
    e = mfma16(ah0, bl0, e); e = mfma16(ah1, bl1, e);
    e = mfma16(al0, bh0, e); e = mfma16(al1, bh1, e);
#pragma unroll
    for (int r = 0; r < 4; ++r) {
      float v = e[r];
      float nm = fmaxf(lmax[r], v);
      lsum[r] = lsum[r] * __expf(lmax[r] - nm) + __expf(v - nm);
      lmax[r] = nm;
    }
  }
#pragma unroll
  for (int r = 0; r < 4; ++r) {
    for (int mk = 1; mk < 16; mk <<= 1) {
      float om = __shfl_xor(lmax[r], mk, 16);
      float os = __shfl_xor(lsum[r], mk, 16);
      float nm = fmaxf(lmax[r], om);
      lsum[r] = lsum[r] * __expf(lmax[r] - nm) + os * __expf(om - nm);
      lmax[r] = nm;
    }
  }
  if (l15 == 0) {
#pragma unroll
    for (int r = 0; r < 4; ++r) {
      redM[w][l4 * 4 + r] = lmax[r];
      redS[w][l4 * 4 + r] = lsum[r];
    }
  }
  __syncthreads();
  if (t < 16) {
    float m = redM[0][t];
    m = fmaxf(m, redM[1][t]); m = fmaxf(m, redM[2][t]); m = fmaxf(m, redM[3][t]);
    float s = 0.f;
#pragma unroll
    for (int w2 = 0; w2 < 4; ++w2) s += redS[w2][t] * __expf(redM[w2][t] - m);
    rm[b * NN + m0 + t] = m;
    irs[b * NN + m0 + t] = 1.0f / s;
  }
}

// ---------------- fused attention apply: D = X - (V att)/(1e-9+colsum) ----------
// Block: 16 n-rows; 4 waves each cover 512 of the m axis; LDS combine.
__global__ __launch_bounds__(256) void k_attnY(const bf16* __restrict__ Qh,
                                               const bf16* __restrict__ Ql,
                                               const bf16* __restrict__ Vh,
                                               const bf16* __restrict__ Vl,
                                               const float* __restrict__ rm,
                                               const float* __restrict__ irs,
                                               const float* __restrict__ Xf,
                                               bf16* __restrict__ Dh,
                                               bf16* __restrict__ Dl) {
  __shared__ alignas(16) bf16 smPh[4][16][40];
  __shared__ alignas(16) bf16 smPl[4][16][40];
  __shared__ float accLds[16][257];
  __shared__ float colLds[16];
  int b = blockIdx.y;
  int t = threadIdx.x, lane = t & 63, w = t >> 6;  // w = m-chunk
  int l15 = lane & 15, l4 = lane >> 4;
  int n0 = blockIdx.x * 16;
  if (t < 16) colLds[t] = 0.f;
  __syncthreads();
  size_t qrow = ((size_t)(b * NN + n0 + l15)) * 64 + l4 * 8;
  short8 qh0 = ldg8(Qh + qrow), qh1 = ldg8(Qh + qrow + 32);
  short8 ql0 = ldg8(Ql + qrow), ql1 = ldg8(Ql + qrow + 32);
  f32x4 zero = {0.f, 0.f, 0.f, 0.f};
  f32x4 acc[16];
#pragma unroll
  for (int ct = 0; ct < 16; ++ct) acc[ct] = zero;
  f32x4 cac = zero;
  for (int mb = w * 16; mb < w * 16 + 16; ++mb) {
    int m0 = mb * 32;
#pragma unroll
    for (int sub = 0; sub < 2; ++sub) {
      int ms = m0 + sub * 16;
      size_t brow = ((size_t)(b * NN + ms + l15)) * 64 + l4 * 8;
      short8 bh0 = ldg8(Qh + brow), bh1 = ldg8(Qh + brow + 32);
      short8 bl0 = ldg8(Ql + brow), bl1 = ldg8(Ql + brow + 32);
      f32x4 e = zero;
      e = mfma16(qh0, bh0, e); e = mfma16(qh1, bh1, e);
      e = mfma16(qh0, bl0, e); e = mfma16(qh1, bl1, e);
      e = mfma16(ql0, bh0, e); e = mfma16(ql1, bh1, e);
      float rmv = rm[b * NN + ms + l15];
      float iv = irs[b * NN + ms + l15];
#pragma unroll
      for (int r = 0; r < 4; ++r) {
        float p = __expf(e[r] - rmv) * iv;
        cac[r] += p;
        bf16 ph, pl;
        split2(p, ph, pl);
        smPh[w][l4 * 4 + r][sub * 16 + l15] = ph;
        smPl[w][l4 * 4 + r][sub * 16 + l15] = pl;
      }
    }
    asm volatile("s_waitcnt lgkmcnt(0)" ::: "memory");
    __builtin_amdgcn_sched_barrier(0);
    short8 pah = *reinterpret_cast<const short8*>(&smPh[w][l15][l4 * 8]);
    short8 pal = *reinterpret_cast<const short8*>(&smPl[w][l15][l4 * 8]);
#pragma unroll
    for (int ct = 0; ct < 16; ++ct) {
      size_t vrow = ((size_t)(b * C + ct * 16 + l15)) * NN + m0 + l4 * 8;
      short8 vh = ldg8(Vh + vrow);
      short8 vl = ldg8(Vl + vrow);
      acc[ct] = mfma16(pah, vh, acc[ct]);
      acc[ct] = mfma16(pah, vl, acc[ct]);
      acc[ct] = mfma16(pal, vh, acc[ct]);
    }
  }
  // colsum: reduce over the 16 lanes (m within tile), then across waves
#pragma unroll
  for (int r = 0; r < 4; ++r) {
    for (int mk = 1; mk < 16; mk <<= 1) cac[r] += __shfl_xor(cac[r], mk, 16);
  }
  if (l15 == 0) {
#pragma unroll
    for (int r = 0; r < 4; ++r) atomicAdd(&colLds[l4 * 4 + r], cac[r]);
  }
  // x_r: combine wave partials in LDS
  if (w == 0) {
#pragma unroll
    for (int ct = 0; ct < 16; ++ct)
#pragma unroll
      for (int r = 0; r < 4; ++r) accLds[l4 * 4 + r][ct * 16 + l15] = acc[ct][r];
  }
  __syncthreads();
  if (w != 0) {
#pragma unroll
    for (int ct = 0; ct < 16; ++ct)
#pragma unroll
      for (int r = 0; r < 4; ++r)
        atomicAdd(&accLds[l4 * 4 + r][ct * 16 + l15], acc[ct][r]);
  }
  __syncthreads();
  // epilogue: 256 threads cover 16 rows x 256 cols
  int row = t >> 4;
  int n = n0 + row;
  float inv = 1.0f / (1e-9f + colLds[row]);
  size_t base = ((size_t)(b * NN + n)) * C;
#pragma unroll
  for (int i = 0; i < 16; ++i) {
    int c = (t & 15) + i * 16;
    float d = Xf[base + c] - accLds[row][c] * inv;
    bf16 h, l;
    split2(d, h, l);
    Dh[base + c] = h; Dl[base + c] = l;
  }
}

// ---------------- BN finish ----------------
__global__ void k_bnfin(const float* __restrict__ sS, const float* __restrict__ sS2,
                        const float* __restrict__ g, const float* __restrict__ bb,
                        float* __restrict__ scale, float* __restrict__ shift) {
  int c = threadIdx.x;
  float cnt = (float)(BB * NN);
  float mean = sS[c] / cnt;
  float var = fmaxf(sS2[c] / cnt - mean * mean, 0.f);
  float sc = g[c] * rsqrtf(var + 1e-5f);
  scale[c] = sc;
  shift[c] = bb[c] - mean * sc;
}

// ---------------- BN + ReLU (+ residual + out write) ----------------
template <bool RES>
__global__ __launch_bounds__(256) void k_bnrelu(const float* __restrict__ Tt,
                                                const float* __restrict__ scale,
                                                const float* __restrict__ shift,
                                                float* __restrict__ Xf,
                                                bf16* __restrict__ Xh,
                                                bf16* __restrict__ Xl,
                                                float* __restrict__ outp, int Loff) {
  int row = blockIdx.x;  // b*NN + n
  int c = threadIdx.x;
  size_t idx = (size_t)row * C + c;
  float v = Tt[idx] * scale[c] + shift[c];
  v = fmaxf(v, 0.f);
  if (RES) v += Xf[idx];
  Xf[idx] = v;
  bf16 h, l;
  split2(v, h, l);
  Xh[idx] = h; Xl[idx] = l;
  if (RES) {
    int b = row >> 11;
    int n = row & (NN - 1);
    outp[((size_t)(b * 1024 + Loff + c)) * NN + n] = v;
  }
}

extern "C" void kernel_launch(void* const* d_in, const int* in_sizes, int n_in,
                              void* d_out, int out_size, void* d_ws, size_t ws_size,
                              hipStream_t stream) {
  const float* x       = (const float*)d_in[0];
  const float* conv1_w = (const float*)d_in[1];
  const float* conv2_w = (const float*)d_in[2];
  const float* bn1_g   = (const float*)d_in[3];
  const float* bn1_b   = (const float*)d_in[4];
  const float* bn2_g   = (const float*)d_in[5];
  const float* bn2_b   = (const float*)d_in[6];
  const float* wqk     = (const float*)d_in[7];
  const float* wv      = (const float*)d_in[8];
  const float* bv      = (const float*)d_in[9];
  const float* wt      = (const float*)d_in[10];
  const float* bt      = (const float*)d_in[11];
  const float* sg      = (const float*)d_in[12];
  const float* sb      = (const float*)d_in[13];
  float* out = (float*)d_out;

  char* p = (char*)d_ws;
  auto take = [&](size_t n) { char* r = p; p += n; return r; };
  bf16* WB1h = (bf16*)take(131072);
  bf16* WB1l = (bf16*)take(131072);
  bf16* WB2h = (bf16*)take(131072);
  bf16* WB2l = (bf16*)take(131072);
  bf16* WBQh = (bf16*)take(131072);
  bf16* WBQl = (bf16*)take(131072);
  bf16* WBVh = (bf16*)take(524288);
  bf16* WBVl = (bf16*)take(524288);
  bf16* WBTh = (bf16*)take(524288);
  bf16* WBTl = (bf16*)take(524288);
  bf16* XTh  = (bf16*)take(8388608);
  bf16* XTl  = (bf16*)take(8388608);
  float* XF  = (float*)take(16777216);
  bf16* QTh  = (bf16*)take(2097152);
  bf16* QTl  = (bf16*)take(2097152);
  bf16* VBh  = (bf16*)take(8388608);
  bf16* VBl  = (bf16*)take(8388608);
  float* TT  = (float*)VBh;  // alias: t-GEMM runs after attnY consumed V
  bf16* DTh  = (bf16*)take(8388608);
  bf16* DTl  = (bf16*)take(8388608);
  float* RM   = (float*)take(65536);
  float* IRS  = (float*)take(65536);
  float* STAT = (float*)take(12288);
  float* SCSH = (float*)take(12288);

  hipMemsetAsync(STAT, 0, 6 * 512 * sizeof(float), stream);
  k_cvt<<<256, 256, 0, stream>>>(conv1_w, WB1h, WB1l, 65536);
  k_cvt<<<256, 256, 0, stream>>>(conv2_w, WB2h, WB2l, 65536);
  k_cvt<<<256, 256, 0, stream>>>(wqk, WBQh, WBQl, 65536);
  k_cvt<<<1024, 256, 0, stream>>>(wv, WBVh, WBVl, 262144);
  k_cvt<<<1024, 256, 0, stream>>>(wt, WBTh, WBTl, 262144);
  k_tin<<<dim3(32, 4, 8), 256, 0, stream>>>(x, XTh, XTl);

  // conv1 + bn1 + relu   (note: TT aliases VB, safe — V not yet used)
  k_gemm_tr<true, false, true><<<dim3(32, 4, 8), 256, 0, stream>>>(
      XTh, XTl, WB1h, WB1l, nullptr, TT, nullptr, nullptr, 256, STAT + 0, STAT + 256);
  k_bnfin<<<1, 256, 0, stream>>>(STAT + 0, STAT + 256, bn1_g, bn1_b, SCSH + 0, SCSH + 256);
  k_bnrelu<false><<<16384, 256, 0, stream>>>(TT, SCSH + 0, SCSH + 256, XF, XTh, XTl, nullptr, 0);

  // conv2 + bn2 + relu
  k_gemm_tr<true, false, true><<<dim3(32, 4, 8), 256, 0, stream>>>(
      XTh, XTl, WB2h, WB2l, nullptr, TT, nullptr, nullptr, 256, STAT + 512, STAT + 768);
  k_bnfin<<<1, 256, 0, stream>>>(STAT + 512, STAT + 768, bn2_g, bn2_b, SCSH + 512, SCSH + 768);
  k_bnrelu<false><<<16384, 256, 0, stream>>>(TT, SCSH + 512, SCSH + 768, XF, XTh, XTl, nullptr, 0);

  for (int L = 0; L < 4; ++L) {
    float* ST = STAT + (2 + L) * 512;
    float* SC = SCSH + (2 + L) * 512;
    // q projection -> Qt hi/lo [B][N][64]
    k_gemm_tr<false, false, false><<<dim3(32, 1, 8), 256, 0, stream>>>(
        XTh, XTl, WBQh + L * 16384, WBQl + L * 16384, nullptr, nullptr, QTh, QTl, 64,
        nullptr, nullptr);
    // v projection -> V hi/lo [B][C][N]
    k_gemm_nm<<<dim3(4, 32, 8), 256, 0, stream>>>(WBVh + L * 65536, WBVl + L * 65536,
                                                  XTh, XTl, bv + L * 256, VBh, VBl);
    // softmax row stats (m-split across waves)
    k_rowstats<<<dim3(128, 8), 256, 0, stream>>>(QTh, QTl, RM, IRS);
    // fused E-recompute + renorm + V-apply + subtract -> D hi/lo (m-split)
    k_attnY<<<dim3(128, 8), 256, 0, stream>>>(QTh, QTl, VBh, VBl, RM, IRS, XF, DTh, DTl);
    // t projection + stats (TT aliases VB — V fully consumed by attnY above)
    k_gemm_tr<true, true, true><<<dim3(32, 4, 8), 256, 0, stream>>>(
        DTh, DTl, WBTh + L * 65536, WBTl + L * 65536, bt + L * 256, TT, nullptr, nullptr,
        256, ST, ST + 256);
    k_bnfin<<<1, 256, 0, stream>>>(ST, ST + 256, sg + L * 256, sb + L * 256, SC, SC + 256);
    // bn + relu + residual + output slice
    k_bnrelu<true><<<16384, 256, 0, stream>>>(TT, SC, SC + 256, XF, XTh, XTl, out, L * 256);
  }
}

// Round 4
// 1207.721 us; speedup vs baseline: 2.0945x; 1.9283x over previous
//
#include <hip/hip_runtime.h>
#include <hip/hip_bf16.h>

typedef __attribute__((ext_vector_type(8))) short short8;
typedef __attribute__((ext_vector_type(4))) float f32x4;
using bf16 = __hip_bfloat16;

constexpr int C  = 256;
constexpr int BB = 8;
constexpr int NN = 2048;

#define DEVI __device__ __forceinline__

DEVI short8 ldg8(const bf16* p) { return *reinterpret_cast<const short8*>(p); }

DEVI f32x4 mfma16(short8 a, short8 b, f32x4 c) {
  return __builtin_amdgcn_mfma_f32_16x16x32_bf16(a, b, c, 0, 0, 0);
}

DEVI void split2(float x, bf16& h, bf16& l) {
  h = __float2bfloat16(x);
  l = __float2bfloat16(x - __bfloat162float(h));
}

DEVI short b2s(bf16 x) { short s; __builtin_memcpy(&s, &x, 2); return s; }

// Universal fragment-swizzled layout: FR(n,k,K) = ((n>>4)*(K>>3) + (k>>3))*128
// + (n&15)*8 + (k&7).  A 16xK row-tile is K/8 blocks of 128 contiguous elems;
// an MFMA fragment load (lane l15=row, l4=k-subchunk) is 1KB contiguous.

// Write one 16x16 MFMA C-tile (lane: col=l15, row=l4*4+r) to swizzled hi/lo
// planes via wave-private LDS transpose. tilebase = elem index of the
// (row-tile, first col-group) block; col-groups advance by 128 elems.
DEVI void store_tile16(const float v[4], bf16* __restrict__ H, bf16* __restrict__ L,
                       size_t tilebase, float* lds, int lane) {
  int l15 = lane & 15, l4 = lane >> 4;
#pragma unroll
  for (int r = 0; r < 4; ++r) lds[(l4 * 4 + r) * 20 + l15] = v[r];
  asm volatile("s_waitcnt lgkmcnt(0)" ::: "memory");
  __builtin_amdgcn_sched_barrier(0);
  int n = lane & 15, cg = (lane >> 4) & 1, pl = lane >> 5;
  short8 o;
#pragma unroll
  for (int j = 0; j < 8; ++j) {
    bf16 h, l;
    split2(lds[n * 20 + cg * 8 + j], h, l);
    o[j] = pl ? b2s(l) : b2s(h);
  }
  bf16* P = pl ? L : H;
  *reinterpret_cast<short8*>(P + tilebase + (size_t)cg * 128 + n * 8) = o;
}

// ---------------- weights fp32 [rows][256] -> swizzled bf16 hi/lo ----------------
__global__ __launch_bounds__(256) void k_cvtW(const float* __restrict__ s,
                                              bf16* __restrict__ dh,
                                              bf16* __restrict__ dl, int rows) {
  int idx = blockIdx.x * 256 + threadIdx.x;
  if (idx >= rows * 32) return;
  int row = idx >> 5, kg = idx & 31;
  const float* sp = s + row * 256 + kg * 8;
  short8 oh, ol;
#pragma unroll
  for (int j = 0; j < 8; ++j) {
    bf16 h, l;
    split2(sp[j], h, l);
    oh[j] = b2s(h); ol[j] = b2s(l);
  }
  size_t off = ((size_t)(row >> 4) * 32 + kg) * 128 + (row & 15) * 8;
  *reinterpret_cast<short8*>(dh + off) = oh;
  *reinterpret_cast<short8*>(dl + off) = ol;
}

// ---------------- x [B][C][N] f32 -> X' swizzled (rows=n, K=256) hi/lo ----------------
__global__ __launch_bounds__(256) void k_tin(const float* __restrict__ x,
                                             bf16* __restrict__ Xh,
                                             bf16* __restrict__ Xl) {
  __shared__ float tile[64][65];
  int b = blockIdx.z, n0 = blockIdx.x * 64, c0 = blockIdx.y * 64;
  int t = threadIdx.x;
  int tn = t & 63, tq = t >> 6;
#pragma unroll
  for (int i = 0; i < 16; ++i) {
    int cc = i * 4 + tq;
    tile[cc][tn] = x[((size_t)(b * C + c0 + cc)) * NN + n0 + tn];
  }
  __syncthreads();
  bf16* XHb = Xh + (size_t)b * NN * C;
  bf16* XLb = Xl + (size_t)b * NN * C;
#pragma unroll
  for (int i = 0; i < 4; ++i) {
    int e = i * 256 + t;          // 1024 emissions: 64 n x 8 cgroups x 2 planes
    int nl = e & 63;
    int cgp = e >> 6;
    int cg = cgp & 7, pl = cgp >> 3;
    short8 o;
#pragma unroll
    for (int j = 0; j < 8; ++j) {
      bf16 h, l;
      split2(tile[cg * 8 + j][nl], h, l);
      o[j] = pl ? b2s(l) : b2s(h);
    }
    int n = n0 + nl;
    size_t off = ((size_t)(n >> 4) * 32 + ((c0 >> 3) + cg)) * 128 + (n & 15) * 8;
    bf16* P = pl ? XLb : XHb;
    *reinterpret_cast<short8*>(P + off) = o;
  }
}

// ------- GEMM: Out[b][n][o] = sum_k A'[b](n,k) W'(o,k) (+bias[o]); A',W' swizzled ------
template <bool OUTF32, bool BIASJ, bool STATS>
__global__ __launch_bounds__(256) void k_gemm_tr(const bf16* __restrict__ Ah,
                                                 const bf16* __restrict__ Al,
                                                 const bf16* __restrict__ Wh,
                                                 const bf16* __restrict__ Wl,
                                                 const float* __restrict__ bias,
                                                 float* __restrict__ OutF,
                                                 bf16* __restrict__ Oh,
                                                 bf16* __restrict__ Ol, int OD,
                                                 float* __restrict__ sS,
                                                 float* __restrict__ sS2) {
  __shared__ float smS[64], smS2[64];
  __shared__ float scratch[4][320];
  int b = blockIdx.z, i0 = blockIdx.x * 64, j0 = blockIdx.y * 64;
  int t = threadIdx.x, lane = t & 63, w = t >> 6;
  int l15 = lane & 15, l4 = lane >> 4;
  if (STATS) {
    if (t < 64) { smS[t] = 0.f; smS2[t] = 0.f; }
    __syncthreads();
  }
  const bf16* Abh = Ah + (size_t)b * NN * C;
  const bf16* Abl = Al + (size_t)b * NN * C;
  int ntile = (i0 >> 4) + w;
  f32x4 acc[4];
#pragma unroll
  for (int ct = 0; ct < 4; ++ct) acc[ct] = f32x4{0.f, 0.f, 0.f, 0.f};
#pragma unroll
  for (int ks = 0; ks < 8; ++ks) {
    int ko = ks * 4 + l4;
    short8 a_h = ldg8(Abh + ((size_t)ntile * 32 + ko) * 128 + l15 * 8);
    short8 a_l = ldg8(Abl + ((size_t)ntile * 32 + ko) * 128 + l15 * 8);
#pragma unroll
    for (int ct = 0; ct < 4; ++ct) {
      size_t wo = ((size_t)((j0 >> 4) + ct) * 32 + ko) * 128 + l15 * 8;
      short8 w_h = ldg8(Wh + wo);
      short8 w_l = ldg8(Wl + wo);
      acc[ct] = mfma16(a_h, w_h, acc[ct]);
      acc[ct] = mfma16(a_h, w_l, acc[ct]);
      acc[ct] = mfma16(a_l, w_h, acc[ct]);
    }
  }
#pragma unroll
  for (int ct = 0; ct < 4; ++ct) {
    float bj = 0.f;
    if (BIASJ) bj = bias[j0 + ct * 16 + l15];
    float v[4];
    float s = 0.f, s2 = 0.f;
#pragma unroll
    for (int r = 0; r < 4; ++r) {
      v[r] = acc[ct][r] + bj;
      if (STATS) { s += v[r]; s2 += v[r] * v[r]; }
    }
    if (OUTF32) {
#pragma unroll
      for (int r = 0; r < 4; ++r) {
        int row = i0 + w * 16 + l4 * 4 + r;
        OutF[((size_t)(b * NN + row)) * OD + j0 + ct * 16 + l15] = v[r];
      }
    } else {
      bf16* Obh = Oh + (size_t)b * NN * OD;
      bf16* Obl = Ol + (size_t)b * NN * OD;
      size_t tb = ((size_t)ntile * (OD >> 3) + ((j0 + ct * 16) >> 3)) * 128;
      store_tile16(v, Obh, Obl, tb, scratch[w], lane);
    }
    if (STATS) {
      s += __shfl_xor(s, 16); s2 += __shfl_xor(s2, 16);
      s += __shfl_xor(s, 32); s2 += __shfl_xor(s2, 32);
      if (l4 == 0) {
        atomicAdd(&smS[ct * 16 + l15], s);
        atomicAdd(&smS2[ct * 16 + l15], s2);
      }
    }
  }
  if (STATS) {
    __syncthreads();
    if (t < 64) {
      atomicAdd(&sS[j0 + t], smS[t]);
      atomicAdd(&sS2[j0 + t], smS2[t]);
    }
  }
}

// ------- V'[b](c,m) = sum_k W'(c,k) X'[b](m,k) + bias[c]; output swizzled rows=c,K=N ---
__global__ __launch_bounds__(256) void k_gemm_nm(const bf16* __restrict__ Wh,
                                                 const bf16* __restrict__ Wl,
                                                 const bf16* __restrict__ Xh,
                                                 const bf16* __restrict__ Xl,
                                                 const float* __restrict__ bias,
                                                 bf16* __restrict__ Vh,
                                                 bf16* __restrict__ Vl) {
  __shared__ float scratch[4][320];
  int b = blockIdx.z, i0 = blockIdx.x * 64, j0 = blockIdx.y * 64;
  int t = threadIdx.x, lane = t & 63, w = t >> 6;
  int l15 = lane & 15, l4 = lane >> 4;
  const bf16* Xbh = Xh + (size_t)b * NN * C;
  const bf16* Xbl = Xl + (size_t)b * NN * C;
  int ntile = (i0 >> 4) + w;
  f32x4 acc[4];
#pragma unroll
  for (int ct = 0; ct < 4; ++ct) acc[ct] = f32x4{0.f, 0.f, 0.f, 0.f};
#pragma unroll
  for (int ks = 0; ks < 8; ++ks) {
    int ko = ks * 4 + l4;
    short8 a_h = ldg8(Wh + ((size_t)ntile * 32 + ko) * 128 + l15 * 8);
    short8 a_l = ldg8(Wl + ((size_t)ntile * 32 + ko) * 128 + l15 * 8);
#pragma unroll
    for (int ct = 0; ct < 4; ++ct) {
      size_t xo = ((size_t)((j0 >> 4) + ct) * 32 + ko) * 128 + l15 * 8;
      short8 x_h = ldg8(Xbh + xo);
      short8 x_l = ldg8(Xbl + xo);
      acc[ct] = mfma16(a_h, x_h, acc[ct]);
      acc[ct] = mfma16(a_h, x_l, acc[ct]);
      acc[ct] = mfma16(a_l, x_h, acc[ct]);
    }
  }
  float br[4];
#pragma unroll
  for (int r = 0; r < 4; ++r) br[r] = bias[i0 + w * 16 + l4 * 4 + r];
  bf16* Vbh = Vh + (size_t)b * C * NN;
  bf16* Vbl = Vl + (size_t)b * C * NN;
#pragma unroll
  for (int ct = 0; ct < 4; ++ct) {
    float v[4];
#pragma unroll
    for (int r = 0; r < 4; ++r) v[r] = acc[ct][r] + br[r];
    size_t tb = ((size_t)ntile * (NN >> 3) + ((j0 + ct * 16) >> 3)) * 128;
    store_tile16(v, Vbh, Vbl, tb, scratch[w], lane);
  }
}

// ---------------- row softmax stats over E = Q Q^T (split 3-term) ----------------
__global__ __launch_bounds__(256) void k_rowstats(const bf16* __restrict__ Qh,
                                                  const bf16* __restrict__ Ql,
                                                  float* __restrict__ rm,
                                                  float* __restrict__ irs) {
  __shared__ float redM[4][16], redS[4][16];
  int b = blockIdx.y;
  int t = threadIdx.x, lane = t & 63, w = t >> 6;
  int l15 = lane & 15, l4 = lane >> 4;
  int mt = blockIdx.x;  // 16-row stat tile
  const bf16* QHb = Qh + (size_t)b * NN * 64;
  const bf16* QLb = Ql + (size_t)b * NN * 64;
  short8 ah0 = ldg8(QHb + ((size_t)mt * 8 + l4) * 128 + l15 * 8);
  short8 ah1 = ldg8(QHb + ((size_t)mt * 8 + 4 + l4) * 128 + l15 * 8);
  short8 al0 = ldg8(QLb + ((size_t)mt * 8 + l4) * 128 + l15 * 8);
  short8 al1 = ldg8(QLb + ((size_t)mt * 8 + 4 + l4) * 128 + l15 * 8);
  float lmax[4], lsum[4];
#pragma unroll
  for (int r = 0; r < 4; ++r) { lmax[r] = -3.4e38f; lsum[r] = 0.f; }
  for (int nb = w * 32; nb < w * 32 + 32; ++nb) {
    short8 bh0 = ldg8(QHb + ((size_t)nb * 8 + l4) * 128 + l15 * 8);
    short8 bh1 = ldg8(QHb + ((size_t)nb * 8 + 4 + l4) * 128 + l15 * 8);
    short8 bl0 = ldg8(QLb + ((size_t)nb * 8 + l4) * 128 + l15 * 8);
    short8 bl1 = ldg8(QLb + ((size_t)nb * 8 + 4 + l4) * 128 + l15 * 8);
    f32x4 e = {0.f, 0.f, 0.f, 0.f};
    e = mfma16(ah0, bh0, e); e = mfma16(ah1, bh1, e);
    e = mfma16(ah0, bl0, e); e = mfma16(ah1, bl1, e);
    e = mfma16(al0, bh0, e); e = mfma16(al1, bh1, e);
#pragma unroll
    for (int r = 0; r < 4; ++r) {
      float v = e[r];
      float nm = fmaxf(lmax[r], v);
      lsum[r] = lsum[r] * __expf(lmax[r] - nm) + __expf(v - nm);
      lmax[r] = nm;
    }
  }
#pragma unroll
  for (int r = 0; r < 4; ++r) {
    for (int mk = 1; mk < 16; mk <<= 1) {
      float om = __shfl_xor(lmax[r], mk, 16);
      float os = __shfl_xor(lsum[r], mk, 16);
      float nm = fmaxf(lmax[r], om);
      lsum[r] = lsum[r] * __expf(lmax[r] - nm) + os * __expf(om - nm);
      lmax[r] = nm;
    }
  }
  if (l15 == 0) {
#pragma unroll
    for (int r = 0; r < 4; ++r) {
      redM[w][l4 * 4 + r] = lmax[r];
      redS[w][l4 * 4 + r] = lsum[r];
    }
  }
  __syncthreads();
  if (t < 16) {
    float m = redM[0][t];
    m = fmaxf(m, redM[1][t]); m = fmaxf(m, redM[2][t]); m = fmaxf(m, redM[3][t]);
    float s = 0.f;
#pragma unroll
    for (int w2 = 0; w2 < 4; ++w2) s += redS[w2][t] * __expf(redM[w2][t] - m);
    rm[b * NN + mt * 16 + t] = m;
    irs[b * NN + mt * 16 + t] = 1.0f / s;
  }
}

// ---------------- fused attention: D' = X - (V att)/(1e-9+colsum), swizzled out ------
// Block: 64 n-rows, 4 waves. Wave w: E/P for n-rows [w*16,w*16+16); PV for
// c-slice [w*64, w*64+64). P shared via double-buffered fragment-linear LDS.
__global__ __launch_bounds__(256) void k_attnY(const bf16* __restrict__ QH,
                                               const bf16* __restrict__ QL,
                                               const bf16* __restrict__ VH,
                                               const bf16* __restrict__ VL,
                                               const float* __restrict__ rm,
                                               const float* __restrict__ irs,
                                               const float* __restrict__ Xf,
                                               bf16* __restrict__ DH,
                                               bf16* __restrict__ DL) {
  __shared__ bf16 Ph[2][2048], Pl[2][2048];
  __shared__ float colLds[64], invLds[64];
  __shared__ float scratch[4][320];
  int b = blockIdx.y, n0 = blockIdx.x * 64;
  int t = threadIdx.x, lane = t & 63, w = t >> 6;
  int l15 = lane & 15, l4 = lane >> 4;
  const bf16* QHb = QH + (size_t)b * NN * 64;
  const bf16* QLb = QL + (size_t)b * NN * 64;
  const bf16* VHb = VH + (size_t)b * C * NN;
  const bf16* VLb = VL + (size_t)b * C * NN;
  const float* rmb = rm + b * NN;
  const float* irb = irs + b * NN;
  int ntq = (n0 >> 4) + w;
  short8 qh0 = ldg8(QHb + ((size_t)ntq * 8 + l4) * 128 + l15 * 8);
  short8 qh1 = ldg8(QHb + ((size_t)ntq * 8 + 4 + l4) * 128 + l15 * 8);
  short8 ql0 = ldg8(QLb + ((size_t)ntq * 8 + l4) * 128 + l15 * 8);
  short8 ql1 = ldg8(QLb + ((size_t)ntq * 8 + 4 + l4) * 128 + l15 * 8);
  f32x4 zero = {0.f, 0.f, 0.f, 0.f};
  f32x4 acc[4][4];
#pragma unroll
  for (int nt = 0; nt < 4; ++nt)
#pragma unroll
    for (int ctl = 0; ctl < 4; ++ctl) acc[nt][ctl] = zero;
  float cac[4] = {0.f, 0.f, 0.f, 0.f};
  for (int s = 0; s < 64; ++s) {
    int m0 = s * 32;
    bf16* phc = Ph[s & 1];
    bf16* plc = Pl[s & 1];
#pragma unroll
    for (int sub = 0; sub < 2; ++sub) {
      int mt = s * 2 + sub;
      short8 bh0 = ldg8(QHb + ((size_t)mt * 8 + l4) * 128 + l15 * 8);
      short8 bh1 = ldg8(QHb + ((size_t)mt * 8 + 4 + l4) * 128 + l15 * 8);
      short8 bl0 = ldg8(QLb + ((size_t)mt * 8 + l4) * 128 + l15 * 8);
      short8 bl1 = ldg8(QLb + ((size_t)mt * 8 + 4 + l4) * 128 + l15 * 8);
      f32x4 e = zero;
      e = mfma16(qh0, bh0, e); e = mfma16(qh1, bh1, e);
      e = mfma16(qh0, bl0, e); e = mfma16(qh1, bl1, e);
      e = mfma16(ql0, bh0, e); e = mfma16(ql1, bh1, e);
      int ms = m0 + sub * 16;
      float rmv = rmb[ms + l15], iv = irb[ms + l15];
#pragma unroll
      for (int r = 0; r < 4; ++r) {
        float p = __expf(e[r] - rmv) * iv;
        cac[r] += p;
        bf16 ph, pl;
        split2(p, ph, pl);
        int mloc = sub * 16 + l15;
        int slot = (w * 4 + (mloc >> 3)) * 128 + (l4 * 4 + r) * 8 + (mloc & 7);
        phc[slot] = ph;
        plc[slot] = pl;
      }
    }
    __syncthreads();
    short8 pah[4], pal[4];
#pragma unroll
    for (int nt = 0; nt < 4; ++nt) {
      pah[nt] = *reinterpret_cast<const short8*>(&phc[(nt * 4 + l4) * 128 + l15 * 8]);
      pal[nt] = *reinterpret_cast<const short8*>(&plc[(nt * 4 + l4) * 128 + l15 * 8]);
    }
#pragma unroll
    for (int ctl = 0; ctl < 4; ++ctl) {
      size_t vo = ((size_t)(w * 4 + ctl) * 256 + (m0 >> 3) + l4) * 128 + l15 * 8;
      short8 vh = ldg8(VHb + vo);
      short8 vl = ldg8(VLb + vo);
#pragma unroll
      for (int nt = 0; nt < 4; ++nt) {
        acc[nt][ctl] = mfma16(pah[nt], vh, acc[nt][ctl]);
        acc[nt][ctl] = mfma16(pah[nt], vl, acc[nt][ctl]);
        acc[nt][ctl] = mfma16(pal[nt], vh, acc[nt][ctl]);
      }
    }
  }
#pragma unroll
  for (int r = 0; r < 4; ++r) {
    float v2 = cac[r];
    v2 += __shfl_xor(v2, 1, 16); v2 += __shfl_xor(v2, 2, 16);
    v2 += __shfl_xor(v2, 4, 16); v2 += __shfl_xor(v2, 8, 16);
    if (l15 == 0) colLds[w * 16 + l4 * 4 + r] = v2;
  }
  __syncthreads();
  if (t < 64) invLds[t] = 1.0f / (1e-9f + colLds[t]);
  __syncthreads();
  bf16* DHb = DH + (size_t)b * NN * C;
  bf16* DLb = DL + (size_t)b * NN * C;
#pragma unroll
  for (int nt = 0; nt < 4; ++nt) {
#pragma unroll
    for (int ctl = 0; ctl < 4; ++ctl) {
      float d[4];
#pragma unroll
      for (int r = 0; r < 4; ++r) {
        int n = n0 + nt * 16 + l4 * 4 + r;
        int c = w * 64 + ctl * 16 + l15;
        d[r] = Xf[((size_t)(b * NN + n)) * C + c] -
               acc[nt][ctl][r] * invLds[nt * 16 + l4 * 4 + r];
      }
      size_t tb = ((size_t)((n0 >> 4) + nt) * 32 + ((w * 64 + ctl * 16) >> 3)) * 128;
      store_tile16(d, DHb, DLb, tb, scratch[w], lane);
    }
  }
}

// ---------------- BN finish ----------------
__global__ void k_bnfin(const float* __restrict__ sS, const float* __restrict__ sS2,
                        const float* __restrict__ g, const float* __restrict__ bb,
                        float* __restrict__ scale, float* __restrict__ shift) {
  int c = threadIdx.x;
  float cnt = (float)(BB * NN);
  float mean = sS[c] / cnt;
  float var = fmaxf(sS2[c] / cnt - mean * mean, 0.f);
  float sc = g[c] * rsqrtf(var + 1e-5f);
  scale[c] = sc;
  shift[c] = bb[c] - mean * sc;
}

// ---------------- BN + ReLU (+ residual + out write); X' swizzled out ----------------
template <bool RES>
__global__ __launch_bounds__(256) void k_bnrelu(const float* __restrict__ Tt,
                                                const float* __restrict__ scale,
                                                const float* __restrict__ shift,
                                                float* __restrict__ Xf,
                                                bf16* __restrict__ Xh,
                                                bf16* __restrict__ Xl,
                                                float* __restrict__ outp, int Loff) {
  int row = blockIdx.x;  // b*NN + n
  int c = threadIdx.x;
  size_t idx = (size_t)row * C + c;
  float v = Tt[idx] * scale[c] + shift[c];
  v = fmaxf(v, 0.f);
  if (RES) v += Xf[idx];
  Xf[idx] = v;
  bf16 h, l;
  split2(v, h, l);
  int b = row >> 11;
  int n = row & (NN - 1);
  size_t off = (size_t)b * NN * C +
               ((size_t)(n >> 4) * 32 + (c >> 3)) * 128 + (n & 15) * 8 + (c & 7);
  Xh[off] = h;
  Xl[off] = l;
  if (RES) {
    outp[((size_t)(b * 1024 + Loff + c)) * NN + n] = v;
  }
}

extern "C" void kernel_launch(void* const* d_in, const int* in_sizes, int n_in,
                              void* d_out, int out_size, void* d_ws, size_t ws_size,
                              hipStream_t stream) {
  const float* x       = (const float*)d_in[0];
  const float* conv1_w = (const float*)d_in[1];
  const float* conv2_w = (const float*)d_in[2];
  const float* bn1_g   = (const float*)d_in[3];
  const float* bn1_b   = (const float*)d_in[4];
  const float* bn2_g   = (const float*)d_in[5];
  const float* bn2_b   = (const float*)d_in[6];
  const float* wqk     = (const float*)d_in[7];
  const float* wv      = (const float*)d_in[8];
  const float* bv      = (const float*)d_in[9];
  const float* wt      = (const float*)d_in[10];
  const float* bt      = (const float*)d_in[11];
  const float* sg      = (const float*)d_in[12];
  const float* sb      = (const float*)d_in[13];
  float* out = (float*)d_out;

  char* p = (char*)d_ws;
  auto take = [&](size_t n) { char* r = p; p += n; return r; };
  bf16* WB1h = (bf16*)take(131072);
  bf16* WB1l = (bf16*)take(131072);
  bf16* WB2h = (bf16*)take(131072);
  bf16* WB2l = (bf16*)take(131072);
  bf16* WBQh = (bf16*)take(131072);
  bf16* WBQl = (bf16*)take(131072);
  bf16* WBVh = (bf16*)take(524288);
  bf16* WBVl = (bf16*)take(524288);
  bf16* WBTh = (bf16*)take(524288);
  bf16* WBTl = (bf16*)take(524288);
  bf16* XTh  = (bf16*)take(8388608);
  bf16* XTl  = (bf16*)take(8388608);
  float* XF  = (float*)take(16777216);
  bf16* QTh  = (bf16*)take(2097152);
  bf16* QTl  = (bf16*)take(2097152);
  bf16* VBh  = (bf16*)take(8388608);
  bf16* VBl  = (bf16*)take(8388608);
  float* TT  = (float*)VBh;  // alias: t-GEMM output written after attnY consumed V
  bf16* DTh  = (bf16*)take(8388608);
  bf16* DTl  = (bf16*)take(8388608);
  float* RM   = (float*)take(65536);
  float* IRS  = (float*)take(65536);
  float* STAT = (float*)take(12288);
  float* SCSH = (float*)take(12288);

  hipMemsetAsync(STAT, 0, 6 * 512 * sizeof(float), stream);
  k_cvtW<<<32, 256, 0, stream>>>(conv1_w, WB1h, WB1l, 256);
  k_cvtW<<<32, 256, 0, stream>>>(conv2_w, WB2h, WB2l, 256);
  k_cvtW<<<32, 256, 0, stream>>>(wqk, WBQh, WBQl, 256);
  k_cvtW<<<128, 256, 0, stream>>>(wv, WBVh, WBVl, 1024);
  k_cvtW<<<128, 256, 0, stream>>>(wt, WBTh, WBTl, 1024);
  k_tin<<<dim3(32, 4, 8), 256, 0, stream>>>(x, XTh, XTl);

  // conv1 + bn1 + relu   (TT aliases VB, safe — V not yet used)
  k_gemm_tr<true, false, true><<<dim3(32, 4, 8), 256, 0, stream>>>(
      XTh, XTl, WB1h, WB1l, nullptr, TT, nullptr, nullptr, 256, STAT + 0, STAT + 256);
  k_bnfin<<<1, 256, 0, stream>>>(STAT + 0, STAT + 256, bn1_g, bn1_b, SCSH + 0, SCSH + 256);
  k_bnrelu<false><<<16384, 256, 0, stream>>>(TT, SCSH + 0, SCSH + 256, XF, XTh, XTl, nullptr, 0);

  // conv2 + bn2 + relu
  k_gemm_tr<true, false, true><<<dim3(32, 4, 8), 256, 0, stream>>>(
      XTh, XTl, WB2h, WB2l, nullptr, TT, nullptr, nullptr, 256, STAT + 512, STAT + 768);
  k_bnfin<<<1, 256, 0, stream>>>(STAT + 512, STAT + 768, bn2_g, bn2_b, SCSH + 512, SCSH + 768);
  k_bnrelu<false><<<16384, 256, 0, stream>>>(TT, SCSH + 512, SCSH + 768, XF, XTh, XTl, nullptr, 0);

  for (int L = 0; L < 4; ++L) {
    float* ST = STAT + (2 + L) * 512;
    float* SC = SCSH + (2 + L) * 512;
    // q projection -> Q' swizzled [B], rows=N, K=64
    k_gemm_tr<false, false, false><<<dim3(32, 1, 8), 256, 0, stream>>>(
        XTh, XTl, WBQh + L * 16384, WBQl + L * 16384, nullptr, nullptr, QTh, QTl, 64,
        nullptr, nullptr);
    // v projection -> V' swizzled [B], rows=C, K=N
    k_gemm_nm<<<dim3(4, 32, 8), 256, 0, stream>>>(WBVh + L * 65536, WBVl + L * 65536,
                                                  XTh, XTl, bv + L * 256, VBh, VBl);
    // softmax row stats
    k_rowstats<<<dim3(128, 8), 256, 0, stream>>>(QTh, QTl, RM, IRS);
    // fused E-recompute + renorm + V-apply + subtract -> D' swizzled
    k_attnY<<<dim3(32, 8), 256, 0, stream>>>(QTh, QTl, VBh, VBl, RM, IRS, XF, DTh, DTl);
    // t projection + stats (TT aliases VB — V fully consumed by attnY above)
    k_gemm_tr<true, true, true><<<dim3(32, 4, 8), 256, 0, stream>>>(
        DTh, DTl, WBTh + L * 65536, WBTl + L * 65536, bt + L * 256, TT, nullptr, nullptr,
        256, ST, ST + 256);
    k_bnfin<<<1, 256, 0, stream>>>(ST, ST + 256, sg + L * 256, sb + L * 256, SC, SC + 256);
    // bn + relu + residual + output slice
    k_bnrelu<true><<<16384, 256, 0, stream>>>(TT, SC, SC + 256, XF, XTh, XTl, out, L * 256);
  }
}

// Round 5
// 1104.003 us; speedup vs baseline: 2.2912x; 1.0939x over previous
//
#include <hip/hip_runtime.h>
#include <hip/hip_bf16.h>

typedef __attribute__((ext_vector_type(8))) short short8;
typedef __attribute__((ext_vector_type(4))) float f32x4;
using bf16 = __hip_bfloat16;

constexpr int C  = 256;
constexpr int BB = 8;
constexpr int NN = 2048;

#define DEVI __device__ __forceinline__

DEVI short8 ldg8(const bf16* p) { return *reinterpret_cast<const short8*>(p); }

DEVI f32x4 mfma16(short8 a, short8 b, f32x4 c) {
  return __builtin_amdgcn_mfma_f32_16x16x32_bf16(a, b, c, 0, 0, 0);
}

DEVI void split2(float x, bf16& h, bf16& l) {
  h = __float2bfloat16(x);
  l = __float2bfloat16(x - __bfloat162float(h));
}

DEVI short b2s(bf16 x) { short s; __builtin_memcpy(&s, &x, 2); return s; }

// Universal fragment-swizzled layout: FR(n,k,K) = ((n>>4)*(K>>3) + (k>>3))*128
// + (n&15)*8 + (k&7).  MFMA fragment load = 1KB contiguous per wave.

DEVI void store_tile16(const float v[4], bf16* __restrict__ H, bf16* __restrict__ L,
                       size_t tilebase, float* lds, int lane) {
  int l15 = lane & 15, l4 = lane >> 4;
#pragma unroll
  for (int r = 0; r < 4; ++r) lds[(l4 * 4 + r) * 20 + l15] = v[r];
  asm volatile("s_waitcnt lgkmcnt(0)" ::: "memory");
  __builtin_amdgcn_sched_barrier(0);
  int n = lane & 15, cg = (lane >> 4) & 1, pl = lane >> 5;
  short8 o;
#pragma unroll
  for (int j = 0; j < 8; ++j) {
    bf16 h, l;
    split2(lds[n * 20 + cg * 8 + j], h, l);
    o[j] = pl ? b2s(l) : b2s(h);
  }
  bf16* P = pl ? L : H;
  *reinterpret_cast<short8*>(P + tilebase + (size_t)cg * 128 + n * 8) = o;
}

// ---------------- weights fp32 [rows][256] -> swizzled bf16 hi/lo ----------------
__global__ __launch_bounds__(256) void k_cvtW(const float* __restrict__ s,
                                              bf16* __restrict__ dh,
                                              bf16* __restrict__ dl, int rows) {
  int idx = blockIdx.x * 256 + threadIdx.x;
  if (idx >= rows * 32) return;
  int row = idx >> 5, kg = idx & 31;
  const float* sp = s + row * 256 + kg * 8;
  short8 oh, ol;
#pragma unroll
  for (int j = 0; j < 8; ++j) {
    bf16 h, l;
    split2(sp[j], h, l);
    oh[j] = b2s(h); ol[j] = b2s(l);
  }
  size_t off = ((size_t)(row >> 4) * 32 + kg) * 128 + (row & 15) * 8;
  *reinterpret_cast<short8*>(dh + off) = oh;
  *reinterpret_cast<short8*>(dl + off) = ol;
}

// ---------------- x [B][C][N] f32 -> X' swizzled (rows=n, K=256) hi/lo ----------------
__global__ __launch_bounds__(256) void k_tin(const float* __restrict__ x,
                                             bf16* __restrict__ Xh,
                                             bf16* __restrict__ Xl) {
  __shared__ float tile[64][65];
  int b = blockIdx.z, n0 = blockIdx.x * 64, c0 = blockIdx.y * 64;
  int t = threadIdx.x;
  int tn = t & 63, tq = t >> 6;
#pragma unroll
  for (int i = 0; i < 16; ++i) {
    int cc = i * 4 + tq;
    tile[cc][tn] = x[((size_t)(b * C + c0 + cc)) * NN + n0 + tn];
  }
  __syncthreads();
  bf16* XHb = Xh + (size_t)b * NN * C;
  bf16* XLb = Xl + (size_t)b * NN * C;
#pragma unroll
  for (int i = 0; i < 4; ++i) {
    int e = i * 256 + t;
    int nl = e & 63;
    int cgp = e >> 6;
    int cg = cgp & 7, pl = cgp >> 3;
    short8 o;
#pragma unroll
    for (int j = 0; j < 8; ++j) {
      bf16 h, l;
      split2(tile[cg * 8 + j][nl], h, l);
      o[j] = pl ? b2s(l) : b2s(h);
    }
    int n = n0 + nl;
    size_t off = ((size_t)(n >> 4) * 32 + ((c0 >> 3) + cg)) * 128 + (n & 15) * 8;
    bf16* P = pl ? XLb : XHb;
    *reinterpret_cast<short8*>(P + off) = o;
  }
}

// ------- GEMM: Out[b][n][o] = sum_k A'[b](n,k) W'(o,k) (+bias[o]); A',W' swizzled ------
template <bool OUTF32, bool BIASJ, bool STATS>
__global__ __launch_bounds__(256) void k_gemm_tr(const bf16* __restrict__ Ah,
                                                 const bf16* __restrict__ Al,
                                                 const bf16* __restrict__ Wh,
                                                 const bf16* __restrict__ Wl,
                                                 const float* __restrict__ bias,
                                                 float* __restrict__ OutF,
                                                 bf16* __restrict__ Oh,
                                                 bf16* __restrict__ Ol, int OD,
                                                 float* __restrict__ sS,
                                                 float* __restrict__ sS2) {
  __shared__ float smS[64], smS2[64];
  __shared__ float scratch[4][320];
  int b = blockIdx.z, i0 = blockIdx.x * 64, j0 = blockIdx.y * 64;
  int t = threadIdx.x, lane = t & 63, w = t >> 6;
  int l15 = lane & 15, l4 = lane >> 4;
  if (STATS) {
    if (t < 64) { smS[t] = 0.f; smS2[t] = 0.f; }
    __syncthreads();
  }
  const bf16* Abh = Ah + (size_t)b * NN * C;
  const bf16* Abl = Al + (size_t)b * NN * C;
  int ntile = (i0 >> 4) + w;
  f32x4 acc[4];
#pragma unroll
  for (int ct = 0; ct < 4; ++ct) acc[ct] = f32x4{0.f, 0.f, 0.f, 0.f};
#pragma unroll
  for (int ks = 0; ks < 8; ++ks) {
    int ko = ks * 4 + l4;
    short8 a_h = ldg8(Abh + ((size_t)ntile * 32 + ko) * 128 + l15 * 8);
    short8 a_l = ldg8(Abl + ((size_t)ntile * 32 + ko) * 128 + l15 * 8);
#pragma unroll
    for (int ct = 0; ct < 4; ++ct) {
      size_t wo = ((size_t)((j0 >> 4) + ct) * 32 + ko) * 128 + l15 * 8;
      short8 w_h = ldg8(Wh + wo);
      short8 w_l = ldg8(Wl + wo);
      acc[ct] = mfma16(a_h, w_h, acc[ct]);
      acc[ct] = mfma16(a_h, w_l, acc[ct]);
      acc[ct] = mfma16(a_l, w_h, acc[ct]);
    }
  }
#pragma unroll
  for (int ct = 0; ct < 4; ++ct) {
    float bj = 0.f;
    if (BIASJ) bj = bias[j0 + ct * 16 + l15];
    float v[4];
    float s = 0.f, s2 = 0.f;
#pragma unroll
    for (int r = 0; r < 4; ++r) {
      v[r] = acc[ct][r] + bj;
      if (STATS) { s += v[r]; s2 += v[r] * v[r]; }
    }
    if (OUTF32) {
#pragma unroll
      for (int r = 0; r < 4; ++r) {
        int row = i0 + w * 16 + l4 * 4 + r;
        OutF[((size_t)(b * NN + row)) * OD + j0 + ct * 16 + l15] = v[r];
      }
    } else {
      bf16* Obh = Oh + (size_t)b * NN * OD;
      bf16* Obl = Ol + (size_t)b * NN * OD;
      size_t tb = ((size_t)ntile * (OD >> 3) + ((j0 + ct * 16) >> 3)) * 128;
      store_tile16(v, Obh, Obl, tb, scratch[w], lane);
    }
    if (STATS) {
      s += __shfl_xor(s, 16); s2 += __shfl_xor(s2, 16);
      s += __shfl_xor(s, 32); s2 += __shfl_xor(s2, 32);
      if (l4 == 0) {
        atomicAdd(&smS[ct * 16 + l15], s);
        atomicAdd(&smS2[ct * 16 + l15], s2);
      }
    }
  }
  if (STATS) {
    __syncthreads();
    if (t < 64) {
      atomicAdd(&sS[j0 + t], smS[t]);
      atomicAdd(&sS2[j0 + t], smS2[t]);
    }
  }
}

// ------- q-projection: one 16-row tile per block, wave w = 16-col ct tile -----------
__global__ __launch_bounds__(256) void k_qproj(const bf16* __restrict__ Xh,
                                               const bf16* __restrict__ Xl,
                                               const bf16* __restrict__ Wh,
                                               const bf16* __restrict__ Wl,
                                               bf16* __restrict__ Qh,
                                               bf16* __restrict__ Ql) {
  __shared__ float scratch[4][320];
  int b = blockIdx.y, ntile = blockIdx.x;
  int t = threadIdx.x, lane = t & 63, w = t >> 6;
  int l15 = lane & 15, l4 = lane >> 4;
  const bf16* Abh = Xh + (size_t)b * NN * C;
  const bf16* Abl = Xl + (size_t)b * NN * C;
  f32x4 acc = {0.f, 0.f, 0.f, 0.f};
#pragma unroll
  for (int ks = 0; ks < 8; ++ks) {
    int ko = ks * 4 + l4;
    short8 a_h = ldg8(Abh + ((size_t)ntile * 32 + ko) * 128 + l15 * 8);
    short8 a_l = ldg8(Abl + ((size_t)ntile * 32 + ko) * 128 + l15 * 8);
    size_t wo = ((size_t)w * 32 + ko) * 128 + l15 * 8;
    short8 w_h = ldg8(Wh + wo);
    short8 w_l = ldg8(Wl + wo);
    acc = mfma16(a_h, w_h, acc);
    acc = mfma16(a_h, w_l, acc);
    acc = mfma16(a_l, w_h, acc);
  }
  float v[4] = {acc[0], acc[1], acc[2], acc[3]};
  size_t tb = ((size_t)ntile * 8 + w * 2) * 128;
  store_tile16(v, Qh + (size_t)b * NN * 64, Ql + (size_t)b * NN * 64, tb,
               scratch[w], lane);
}

// ------- V'[b](c,m) = sum_k W'(c,k) X'[b](m,k) + bias[c]; output swizzled rows=c,K=N ---
__global__ __launch_bounds__(256) void k_gemm_nm(const bf16* __restrict__ Wh,
                                                 const bf16* __restrict__ Wl,
                                                 const bf16* __restrict__ Xh,
                                                 const bf16* __restrict__ Xl,
                                                 const float* __restrict__ bias,
                                                 bf16* __restrict__ Vh,
                                                 bf16* __restrict__ Vl) {
  __shared__ float scratch[4][320];
  int b = blockIdx.z, i0 = blockIdx.x * 64, j0 = blockIdx.y * 64;
  int t = threadIdx.x, lane = t & 63, w = t >> 6;
  int l15 = lane & 15, l4 = lane >> 4;
  const bf16* Xbh = Xh + (size_t)b * NN * C;
  const bf16* Xbl = Xl + (size_t)b * NN * C;
  int ntile = (i0 >> 4) + w;
  f32x4 acc[4];
#pragma unroll
  for (int ct = 0; ct < 4; ++ct) acc[ct] = f32x4{0.f, 0.f, 0.f, 0.f};
#pragma unroll
  for (int ks = 0; ks < 8; ++ks) {
    int ko = ks * 4 + l4;
    short8 a_h = ldg8(Wh + ((size_t)ntile * 32 + ko) * 128 + l15 * 8);
    short8 a_l = ldg8(Wl + ((size_t)ntile * 32 + ko) * 128 + l15 * 8);
#pragma unroll
    for (int ct = 0; ct < 4; ++ct) {
      size_t xo = ((size_t)((j0 >> 4) + ct) * 32 + ko) * 128 + l15 * 8;
      short8 x_h = ldg8(Xbh + xo);
      short8 x_l = ldg8(Xbl + xo);
      acc[ct] = mfma16(a_h, x_h, acc[ct]);
      acc[ct] = mfma16(a_h, x_l, acc[ct]);
      acc[ct] = mfma16(a_l, x_h, acc[ct]);
    }
  }
  float br[4];
#pragma unroll
  for (int r = 0; r < 4; ++r) br[r] = bias[i0 + w * 16 + l4 * 4 + r];
  bf16* Vbh = Vh + (size_t)b * C * NN;
  bf16* Vbl = Vl + (size_t)b * C * NN;
#pragma unroll
  for (int ct = 0; ct < 4; ++ct) {
    float v[4];
#pragma unroll
    for (int r = 0; r < 4; ++r) v[r] = acc[ct][r] + br[r];
    size_t tb = ((size_t)ntile * (NN >> 3) + ((j0 + ct * 16) >> 3)) * 128;
    store_tile16(v, Vbh, Vbl, tb, scratch[w], lane);
  }
}

// ---------------- row softmax stats over E = Q Q^T (split 3-term) ----------------
__global__ __launch_bounds__(256) void k_rowstats(const bf16* __restrict__ Qh,
                                                  const bf16* __restrict__ Ql,
                                                  float* __restrict__ rm,
                                                  float* __restrict__ irs) {
  __shared__ float redM[4][16], redS[4][16];
  int b = blockIdx.y;
  int t = threadIdx.x, lane = t & 63, w = t >> 6;
  int l15 = lane & 15, l4 = lane >> 4;
  int mt = blockIdx.x;
  const bf16* QHb = Qh + (size_t)b * NN * 64;
  const bf16* QLb = Ql + (size_t)b * NN * 64;
  short8 ah0 = ldg8(QHb + ((size_t)mt * 8 + l4) * 128 + l15 * 8);
  short8 ah1 = ldg8(QHb + ((size_t)mt * 8 + 4 + l4) * 128 + l15 * 8);
  short8 al0 = ldg8(QLb + ((size_t)mt * 8 + l4) * 128 + l15 * 8);
  short8 al1 = ldg8(QLb + ((size_t)mt * 8 + 4 + l4) * 128 + l15 * 8);
  float lmax[4], lsum[4];
#pragma unroll
  for (int r = 0; r < 4; ++r) { lmax[r] = -3.4e38f; lsum[r] = 0.f; }
  for (int nb = w * 32; nb < w * 32 + 32; ++nb) {
    short8 bh0 = ldg8(QHb + ((size_t)nb * 8 + l4) * 128 + l15 * 8);
    short8 bh1 = ldg8(QHb + ((size_t)nb * 8 + 4 + l4) * 128 + l15 * 8);
    short8 bl0 = ldg8(QLb + ((size_t)nb * 8 + l4) * 128 + l15 * 8);
    short8 bl1 = ldg8(QLb + ((size_t)nb * 8 + 4 + l4) * 128 + l15 * 8);
    f32x4 e = {0.f, 0.f, 0.f, 0.f};
    e = mfma16(ah0, bh0, e); e = mfma16(ah1, bh1, e);
    e = mfma16(ah0, bl0, e); e = mfma16(ah1, bl1, e);
    e = mfma16(al0, bh0, e); e = mfma16(al1, bh1, e);
#pragma unroll
    for (int r = 0; r < 4; ++r) {
      float v = e[r];
      float nm = fmaxf(lmax[r], v);
      lsum[r] = lsum[r] * __expf(lmax[r] - nm) + __expf(v - nm);
      lmax[r] = nm;
    }
  }
#pragma unroll
  for (int r = 0; r < 4; ++r) {
    for (int mk = 1; mk < 16; mk <<= 1) {
      float om = __shfl_xor(lmax[r], mk, 16);
      float os = __shfl_xor(lsum[r], mk, 16);
      float nm = fmaxf(lmax[r], om);
      lsum[r] = lsum[r] * __expf(lmax[r] - nm) + os * __expf(om - nm);
      lmax[r] = nm;
    }
  }
  if (l15 == 0) {
#pragma unroll
    for (int r = 0; r < 4; ++r) {
      redM[w][l4 * 4 + r] = lmax[r];
      redS[w][l4 * 4 + r] = lsum[r];
    }
  }
  __syncthreads();
  if (t < 16) {
    float m = redM[0][t];
    m = fmaxf(m, redM[1][t]); m = fmaxf(m, redM[2][t]); m = fmaxf(m, redM[3][t]);
    float s = 0.f;
#pragma unroll
    for (int w2 = 0; w2 < 4; ++w2) s += redS[w2][t] * __expf(redM[w2][t] - m);
    rm[b * NN + mt * 16 + t] = m;
    irs[b * NN + mt * 16 + t] = 1.0f / s;
  }
}

// ---------------- fused attention: D' = X - (V att)/(1e-9+colsum), swizzled out ------
// Grid (n-tiles, 4 c-blocks, B). Block: 64 n-rows x 64 channels, 4 waves.
// Wave w: produces P for rows [w*16,w*16+16); consumes 16 channels c0+w*16.
// Q-fragment loads software-pipelined across the barrier.
__global__ __launch_bounds__(256) void k_attnY(const bf16* __restrict__ QH,
                                               const bf16* __restrict__ QL,
                                               const bf16* __restrict__ VH,
                                               const bf16* __restrict__ VL,
                                               const float* __restrict__ rm,
                                               const float* __restrict__ irs,
                                               const float* __restrict__ Xf,
                                               bf16* __restrict__ DH,
                                               bf16* __restrict__ DL) {
  __shared__ bf16 Ph[2][2048], Pl[2][2048];
  __shared__ float colLds[64], invLds[64];
  __shared__ float scratch[4][320];
  int b = blockIdx.z, n0 = blockIdx.x * 64, c0 = blockIdx.y * 64;
  int t = threadIdx.x, lane = t & 63, w = t >> 6;
  int l15 = lane & 15, l4 = lane >> 4;
  const bf16* QHb = QH + (size_t)b * NN * 64;
  const bf16* QLb = QL + (size_t)b * NN * 64;
  const bf16* VHb = VH + (size_t)b * C * NN;
  const bf16* VLb = VL + (size_t)b * C * NN;
  const float* rmb = rm + b * NN;
  const float* irb = irs + b * NN;
  int ntq = (n0 >> 4) + w;
  short8 qh0 = ldg8(QHb + ((size_t)ntq * 8 + l4) * 128 + l15 * 8);
  short8 qh1 = ldg8(QHb + ((size_t)ntq * 8 + 4 + l4) * 128 + l15 * 8);
  short8 ql0 = ldg8(QLb + ((size_t)ntq * 8 + l4) * 128 + l15 * 8);
  short8 ql1 = ldg8(QLb + ((size_t)ntq * 8 + 4 + l4) * 128 + l15 * 8);
  int vrow = (c0 >> 4) + w;
  f32x4 zero = {0.f, 0.f, 0.f, 0.f};
  f32x4 acc[4];
#pragma unroll
  for (int nt = 0; nt < 4; ++nt) acc[nt] = zero;
  float cac[4] = {0.f, 0.f, 0.f, 0.f};
  short8 cur[4], nxt[4], s1f[4];

#define LDQ(DST, MT)                                                        \
  DST[0] = ldg8(QHb + ((size_t)(MT) * 8 + l4) * 128 + l15 * 8);             \
  DST[1] = ldg8(QHb + ((size_t)(MT) * 8 + 4 + l4) * 128 + l15 * 8);         \
  DST[2] = ldg8(QLb + ((size_t)(MT) * 8 + l4) * 128 + l15 * 8);             \
  DST[3] = ldg8(QLb + ((size_t)(MT) * 8 + 4 + l4) * 128 + l15 * 8);

#define ESUB(F, MS, PAR, SUB)                                               \
  {                                                                         \
    f32x4 eA = zero, eB = zero;                                             \
    eA = mfma16(qh0, F[0], eA); eB = mfma16(qh1, F[1], eB);                 \
    eA = mfma16(qh0, F[2], eA); eB = mfma16(qh1, F[3], eB);                 \
    eA = mfma16(ql0, F[0], eA); eB = mfma16(ql1, F[1], eB);                 \
    float rmv = rmb[(MS) + l15], iv = irb[(MS) + l15];                      \
    _Pragma("unroll")                                                       \
    for (int r = 0; r < 4; ++r) {                                           \
      float p = __expf(eA[r] + eB[r] - rmv) * iv;                           \
      cac[r] += p;                                                          \
      bf16 ph_, pl_;                                                        \
      split2(p, ph_, pl_);                                                  \
      int slot = (w * 4 + (SUB)*2 + (l15 >> 3)) * 128 + (l4 * 4 + r) * 8 +  \
                 (l15 & 7);                                                 \
      Ph[PAR][slot] = ph_;                                                  \
      Pl[PAR][slot] = pl_;                                                  \
    }                                                                       \
  }

#define BODY(CUR, NXT, S, PAR)                                              \
  {                                                                         \
    LDQ(s1f, (S)*2 + 1)                                                     \
    ESUB(CUR, (S)*32, PAR, 0)                                               \
    ESUB(s1f, (S)*32 + 16, PAR, 1)                                          \
    int mtn = ((S) < 63 ? (S) + 1 : 63) * 2;                                \
    LDQ(NXT, mtn)                                                           \
    short8 vh = ldg8(VHb + ((size_t)vrow * 256 + (S)*4 + l4) * 128 + l15 * 8); \
    short8 vl = ldg8(VLb + ((size_t)vrow * 256 + (S)*4 + l4) * 128 + l15 * 8); \
    __syncthreads();                                                        \
    _Pragma("unroll")                                                       \
    for (int nt = 0; nt < 4; ++nt) {                                        \
      short8 pah = *reinterpret_cast<const short8*>(                        \
          &Ph[PAR][(nt * 4 + l4) * 128 + l15 * 8]);                         \
      short8 pal = *reinterpret_cast<const short8*>(                        \
          &Pl[PAR][(nt * 4 + l4) * 128 + l15 * 8]);                         \
      acc[nt] = mfma16(pah, vh, acc[nt]);                                   \
      acc[nt] = mfma16(pah, vl, acc[nt]);                                   \
      acc[nt] = mfma16(pal, vh, acc[nt]);                                   \
    }                                                                       \
  }

  LDQ(cur, 0)
  for (int sp = 0; sp < 32; ++sp) {
    BODY(cur, nxt, sp * 2, 0)
    BODY(nxt, cur, sp * 2 + 1, 1)
  }
#undef BODY
#undef ESUB
#undef LDQ

#pragma unroll
  for (int r = 0; r < 4; ++r) {
    float v2 = cac[r];
    v2 += __shfl_xor(v2, 1, 16); v2 += __shfl_xor(v2, 2, 16);
    v2 += __shfl_xor(v2, 4, 16); v2 += __shfl_xor(v2, 8, 16);
    if (l15 == 0) colLds[w * 16 + l4 * 4 + r] = v2;
  }
  __syncthreads();
  if (t < 64) invLds[t] = 1.0f / (1e-9f + colLds[t]);
  __syncthreads();
  bf16* DHb = DH + (size_t)b * NN * C;
  bf16* DLb = DL + (size_t)b * NN * C;
#pragma unroll
  for (int nt = 0; nt < 4; ++nt) {
    float d[4];
#pragma unroll
    for (int r = 0; r < 4; ++r) {
      int n = n0 + nt * 16 + l4 * 4 + r;
      int cidx = c0 + w * 16 + l15;
      d[r] = Xf[((size_t)(b * NN + n)) * C + cidx] -
             acc[nt][r] * invLds[nt * 16 + l4 * 4 + r];
    }
    size_t tb = ((size_t)((n0 >> 4) + nt) * 32 + ((c0 + w * 16) >> 3)) * 128;
    store_tile16(d, DHb, DLb, tb, scratch[w], lane);
  }
}

// ---------------- BN finish ----------------
__global__ void k_bnfin(const float* __restrict__ sS, const float* __restrict__ sS2,
                        const float* __restrict__ g, const float* __restrict__ bb,
                        float* __restrict__ scale, float* __restrict__ shift) {
  int c = threadIdx.x;
  float cnt = (float)(BB * NN);
  float mean = sS[c] / cnt;
  float var = fmaxf(sS2[c] / cnt - mean * mean, 0.f);
  float sc = g[c] * rsqrtf(var + 1e-5f);
  scale[c] = sc;
  shift[c] = bb[c] - mean * sc;
}

// ---------------- BN + ReLU (+ residual + out write); X' swizzled out ----------------
template <bool RES>
__global__ __launch_bounds__(256) void k_bnrelu(const float* __restrict__ Tt,
                                                const float* __restrict__ scale,
                                                const float* __restrict__ shift,
                                                float* __restrict__ Xf,
                                                bf16* __restrict__ Xh,
                                                bf16* __restrict__ Xl,
                                                float* __restrict__ outp, int Loff) {
  int row = blockIdx.x;  // b*NN + n
  int c = threadIdx.x;
  size_t idx = (size_t)row * C + c;
  float v = Tt[idx] * scale[c] + shift[c];
  v = fmaxf(v, 0.f);
  if (RES) v += Xf[idx];
  Xf[idx] = v;
  bf16 h, l;
  split2(v, h, l);
  int b = row >> 11;
  int n = row & (NN - 1);
  size_t off = (size_t)b * NN * C +
               ((size_t)(n >> 4) * 32 + (c >> 3)) * 128 + (n & 15) * 8 + (c & 7);
  Xh[off] = h;
  Xl[off] = l;
  if (RES) {
    outp[((size_t)(b * 1024 + Loff + c)) * NN + n] = v;
  }
}

extern "C" void kernel_launch(void* const* d_in, const int* in_sizes, int n_in,
                              void* d_out, int out_size, void* d_ws, size_t ws_size,
                              hipStream_t stream) {
  const float* x       = (const float*)d_in[0];
  const float* conv1_w = (const float*)d_in[1];
  const float* conv2_w = (const float*)d_in[2];
  const float* bn1_g   = (const float*)d_in[3];
  const float* bn1_b   = (const float*)d_in[4];
  const float* bn2_g   = (const float*)d_in[5];
  const float* bn2_b   = (const float*)d_in[6];
  const float* wqk     = (const float*)d_in[7];
  const float* wv      = (const float*)d_in[8];
  const float* bv      = (const float*)d_in[9];
  const float* wt      = (const float*)d_in[10];
  const float* bt      = (const float*)d_in[11];
  const float* sg      = (const float*)d_in[12];
  const float* sb      = (const float*)d_in[13];
  float* out = (float*)d_out;

  char* p = (char*)d_ws;
  auto take = [&](size_t n) { char* r = p; p += n; return r; };
  bf16* WB1h = (bf16*)take(131072);
  bf16* WB1l = (bf16*)take(131072);
  bf16* WB2h = (bf16*)take(131072);
  bf16* WB2l = (bf16*)take(131072);
  bf16* WBQh = (bf16*)take(131072);
  bf16* WBQl = (bf16*)take(131072);
  bf16* WBVh = (bf16*)take(524288);
  bf16* WBVl = (bf16*)take(524288);
  bf16* WBTh = (bf16*)take(524288);
  bf16* WBTl = (bf16*)take(524288);
  bf16* XTh  = (bf16*)take(8388608);
  bf16* XTl  = (bf16*)take(8388608);
  float* XF  = (float*)take(16777216);
  bf16* QTh  = (bf16*)take(2097152);
  bf16* QTl  = (bf16*)take(2097152);
  bf16* VBh  = (bf16*)take(8388608);
  bf16* VBl  = (bf16*)take(8388608);
  float* TT  = (float*)VBh;  // alias: t-GEMM output written after attnY consumed V
  bf16* DTh  = (bf16*)take(8388608);
  bf16* DTl  = (bf16*)take(8388608);
  float* RM   = (float*)take(65536);
  float* IRS  = (float*)take(65536);
  float* STAT = (float*)take(12288);
  float* SCSH = (float*)take(12288);

  hipMemsetAsync(STAT, 0, 6 * 512 * sizeof(float), stream);
  k_cvtW<<<32, 256, 0, stream>>>(conv1_w, WB1h, WB1l, 256);
  k_cvtW<<<32, 256, 0, stream>>>(conv2_w, WB2h, WB2l, 256);
  k_cvtW<<<32, 256, 0, stream>>>(wqk, WBQh, WBQl, 256);
  k_cvtW<<<128, 256, 0, stream>>>(wv, WBVh, WBVl, 1024);
  k_cvtW<<<128, 256, 0, stream>>>(wt, WBTh, WBTl, 1024);
  k_tin<<<dim3(32, 4, 8), 256, 0, stream>>>(x, XTh, XTl);

  // conv1 + bn1 + relu   (TT aliases VB, safe — V not yet used)
  k_gemm_tr<true, false, true><<<dim3(32, 4, 8), 256, 0, stream>>>(
      XTh, XTl, WB1h, WB1l, nullptr, TT, nullptr, nullptr, 256, STAT + 0, STAT + 256);
  k_bnfin<<<1, 256, 0, stream>>>(STAT + 0, STAT + 256, bn1_g, bn1_b, SCSH + 0, SCSH + 256);
  k_bnrelu<false><<<16384, 256, 0, stream>>>(TT, SCSH + 0, SCSH + 256, XF, XTh, XTl, nullptr, 0);

  // conv2 + bn2 + relu
  k_gemm_tr<true, false, true><<<dim3(32, 4, 8), 256, 0, stream>>>(
      XTh, XTl, WB2h, WB2l, nullptr, TT, nullptr, nullptr, 256, STAT + 512, STAT + 768);
  k_bnfin<<<1, 256, 0, stream>>>(STAT + 512, STAT + 768, bn2_g, bn2_b, SCSH + 512, SCSH + 768);
  k_bnrelu<false><<<16384, 256, 0, stream>>>(TT, SCSH + 512, SCSH + 768, XF, XTh, XTl, nullptr, 0);

  for (int L = 0; L < 4; ++L) {
    float* ST = STAT + (2 + L) * 512;
    float* SC = SCSH + (2 + L) * 512;
    // q projection -> Q' swizzled [B], rows=N, K=64
    k_qproj<<<dim3(128, 8), 256, 0, stream>>>(XTh, XTl, WBQh + L * 16384,
                                              WBQl + L * 16384, QTh, QTl);
    // v projection -> V' swizzled [B], rows=C, K=N
    k_gemm_nm<<<dim3(4, 32, 8), 256, 0, stream>>>(WBVh + L * 65536, WBVl + L * 65536,
                                                  XTh, XTl, bv + L * 256, VBh, VBl);
    // softmax row stats
    k_rowstats<<<dim3(128, 8), 256, 0, stream>>>(QTh, QTl, RM, IRS);
    // fused E-recompute + renorm + V-apply + subtract -> D' swizzled
    k_attnY<<<dim3(32, 4, 8), 256, 0, stream>>>(QTh, QTl, VBh, VBl, RM, IRS, XF, DTh, DTl);
    // t projection + stats (TT aliases VB — V fully consumed by attnY above)
    k_gemm_tr<true, true, true><<<dim3(32, 4, 8), 256, 0, stream>>>(
        DTh, DTl, WBTh + L * 65536, WBTl + L * 65536, bt + L * 256, TT, nullptr, nullptr,
        256, ST, ST + 256);
    k_bnfin<<<1, 256, 0, stream>>>(ST, ST + 256, sg + L * 256, sb + L * 256, SC, SC + 256);
    // bn + relu + residual + output slice
    k_bnrelu<true><<<16384, 256, 0, stream>>>(TT, SC, SC + 256, XF, XTh, XTl, out, L * 256);
  }
}

// Round 6
// 973.390 us; speedup vs baseline: 2.5987x; 1.1342x over previous
//
#include <hip/hip_runtime.h>
#include <hip/hip_bf16.h>

typedef __attribute__((ext_vector_type(8))) short short8;
typedef __attribute__((ext_vector_type(4))) float f32x4;
using bf16 = __hip_bfloat16;

constexpr int C  = 256;
constexpr int BB = 8;
constexpr int NN = 2048;

#define DEVI __device__ __forceinline__

DEVI short8 ldg8(const bf16* p) { return *reinterpret_cast<const short8*>(p); }

DEVI f32x4 mfma16(short8 a, short8 b, f32x4 c) {
  return __builtin_amdgcn_mfma_f32_16x16x32_bf16(a, b, c, 0, 0, 0);
}

DEVI void split2(float x, bf16& h, bf16& l) {
  h = __float2bfloat16(x);
  l = __float2bfloat16(x - __bfloat162float(h));
}

DEVI short b2s(bf16 x) { short s; __builtin_memcpy(&s, &x, 2); return s; }

// Universal fragment-swizzled layout: FR(n,k,K) = ((n>>4)*(K>>3) + (k>>3))*128
// + (n&15)*8 + (k&7).  MFMA fragment load = 1KB contiguous per wave.

DEVI void store_tile16(const float v[4], bf16* __restrict__ H, bf16* __restrict__ L,
                       size_t tilebase, float* lds, int lane) {
  int l15 = lane & 15, l4 = lane >> 4;
#pragma unroll
  for (int r = 0; r < 4; ++r) lds[(l4 * 4 + r) * 20 + l15] = v[r];
  asm volatile("s_waitcnt lgkmcnt(0)" ::: "memory");
  __builtin_amdgcn_sched_barrier(0);
  int n = lane & 15, cg = (lane >> 4) & 1, pl = lane >> 5;
  short8 o;
#pragma unroll
  for (int j = 0; j < 8; ++j) {
    bf16 h, l;
    split2(lds[n * 20 + cg * 8 + j], h, l);
    o[j] = pl ? b2s(l) : b2s(h);
  }
  bf16* P = pl ? L : H;
  *reinterpret_cast<short8*>(P + tilebase + (size_t)cg * 128 + n * 8) = o;
}

// ---------------- weights fp32 [rows][256] -> swizzled bf16 hi/lo ----------------
__global__ __launch_bounds__(256) void k_cvtW(const float* __restrict__ s,
                                              bf16* __restrict__ dh,
                                              bf16* __restrict__ dl, int rows) {
  int idx = blockIdx.x * 256 + threadIdx.x;
  if (idx >= rows * 32) return;
  int row = idx >> 5, kg = idx & 31;
  const float* sp = s + row * 256 + kg * 8;
  short8 oh, ol;
#pragma unroll
  for (int j = 0; j < 8; ++j) {
    bf16 h, l;
    split2(sp[j], h, l);
    oh[j] = b2s(h); ol[j] = b2s(l);
  }
  size_t off = ((size_t)(row >> 4) * 32 + kg) * 128 + (row & 15) * 8;
  *reinterpret_cast<short8*>(dh + off) = oh;
  *reinterpret_cast<short8*>(dl + off) = ol;
}

// ---------------- x [B][C][N] f32 -> X' swizzled (rows=n, K=256) hi/lo ----------------
__global__ __launch_bounds__(256) void k_tin(const float* __restrict__ x,
                                             bf16* __restrict__ Xh,
                                             bf16* __restrict__ Xl) {
  __shared__ float tile[64][65];
  int b = blockIdx.z, n0 = blockIdx.x * 64, c0 = blockIdx.y * 64;
  int t = threadIdx.x;
  int tn = t & 63, tq = t >> 6;
#pragma unroll
  for (int i = 0; i < 16; ++i) {
    int cc = i * 4 + tq;
    tile[cc][tn] = x[((size_t)(b * C + c0 + cc)) * NN + n0 + tn];
  }
  __syncthreads();
  bf16* XHb = Xh + (size_t)b * NN * C;
  bf16* XLb = Xl + (size_t)b * NN * C;
#pragma unroll
  for (int i = 0; i < 4; ++i) {
    int e = i * 256 + t;
    int nl = e & 63;
    int cgp = e >> 6;
    int cg = cgp & 7, pl = cgp >> 3;
    short8 o;
#pragma unroll
    for (int j = 0; j < 8; ++j) {
      bf16 h, l;
      split2(tile[cg * 8 + j][nl], h, l);
      o[j] = pl ? b2s(l) : b2s(h);
    }
    int n = n0 + nl;
    size_t off = ((size_t)(n >> 4) * 32 + ((c0 >> 3) + cg)) * 128 + (n & 15) * 8;
    bf16* P = pl ? XLb : XHb;
    *reinterpret_cast<short8*>(P + off) = o;
  }
}

// ------- GEMM: Out[b][n][o] = sum_k A'[b](n,k) W'(o,k) (+bias[o]); A',W' swizzled ------
template <bool OUTF32, bool BIASJ, bool STATS>
__global__ __launch_bounds__(256) void k_gemm_tr(const bf16* __restrict__ Ah,
                                                 const bf16* __restrict__ Al,
                                                 const bf16* __restrict__ Wh,
                                                 const bf16* __restrict__ Wl,
                                                 const float* __restrict__ bias,
                                                 float* __restrict__ OutF,
                                                 bf16* __restrict__ Oh,
                                                 bf16* __restrict__ Ol, int OD,
                                                 float* __restrict__ sS,
                                                 float* __restrict__ sS2) {
  __shared__ float smS[64], smS2[64];
  __shared__ float scratch[4][320];
  int b = blockIdx.z, i0 = blockIdx.x * 64, j0 = blockIdx.y * 64;
  int t = threadIdx.x, lane = t & 63, w = t >> 6;
  int l15 = lane & 15, l4 = lane >> 4;
  if (STATS) {
    if (t < 64) { smS[t] = 0.f; smS2[t] = 0.f; }
    __syncthreads();
  }
  const bf16* Abh = Ah + (size_t)b * NN * C;
  const bf16* Abl = Al + (size_t)b * NN * C;
  int ntile = (i0 >> 4) + w;
  f32x4 acc[4];
#pragma unroll
  for (int ct = 0; ct < 4; ++ct) acc[ct] = f32x4{0.f, 0.f, 0.f, 0.f};
#pragma unroll
  for (int ks = 0; ks < 8; ++ks) {
    int ko = ks * 4 + l4;
    short8 a_h = ldg8(Abh + ((size_t)ntile * 32 + ko) * 128 + l15 * 8);
    short8 a_l = ldg8(Abl + ((size_t)ntile * 32 + ko) * 128 + l15 * 8);
#pragma unroll
    for (int ct = 0; ct < 4; ++ct) {
      size_t wo = ((size_t)((j0 >> 4) + ct) * 32 + ko) * 128 + l15 * 8;
      short8 w_h = ldg8(Wh + wo);
      short8 w_l = ldg8(Wl + wo);
      acc[ct] = mfma16(a_h, w_h, acc[ct]);
      acc[ct] = mfma16(a_h, w_l, acc[ct]);
      acc[ct] = mfma16(a_l, w_h, acc[ct]);
    }
  }
#pragma unroll
  for (int ct = 0; ct < 4; ++ct) {
    float bj = 0.f;
    if (BIASJ) bj = bias[j0 + ct * 16 + l15];
    float v[4];
    float s = 0.f, s2 = 0.f;
#pragma unroll
    for (int r = 0; r < 4; ++r) {
      v[r] = acc[ct][r] + bj;
      if (STATS) { s += v[r]; s2 += v[r] * v[r]; }
    }
    if (OUTF32) {
#pragma unroll
      for (int r = 0; r < 4; ++r) {
        int row = i0 + w * 16 + l4 * 4 + r;
        OutF[((size_t)(b * NN + row)) * OD + j0 + ct * 16 + l15] = v[r];
      }
    } else {
      bf16* Obh = Oh + (size_t)b * NN * OD;
      bf16* Obl = Ol + (size_t)b * NN * OD;
      size_t tb = ((size_t)ntile * (OD >> 3) + ((j0 + ct * 16) >> 3)) * 128;
      store_tile16(v, Obh, Obl, tb, scratch[w], lane);
    }
    if (STATS) {
      s += __shfl_xor(s, 16); s2 += __shfl_xor(s2, 16);
      s += __shfl_xor(s, 32); s2 += __shfl_xor(s2, 32);
      if (l4 == 0) {
        atomicAdd(&smS[ct * 16 + l15], s);
        atomicAdd(&smS2[ct * 16 + l15], s2);
      }
    }
  }
  if (STATS) {
    __syncthreads();
    if (t < 64) {
      atomicAdd(&sS[j0 + t], smS[t]);
      atomicAdd(&sS2[j0 + t], smS2[t]);
    }
  }
}

// ------- q-projection: one 16-row tile per block, wave w = 16-col ct tile -----------
__global__ __launch_bounds__(256) void k_qproj(const bf16* __restrict__ Xh,
                                               const bf16* __restrict__ Xl,
                                               const bf16* __restrict__ Wh,
                                               const bf16* __restrict__ Wl,
                                               bf16* __restrict__ Qh,
                                               bf16* __restrict__ Ql) {
  __shared__ float scratch[4][320];
  int b = blockIdx.y, ntile = blockIdx.x;
  int t = threadIdx.x, lane = t & 63, w = t >> 6;
  int l15 = lane & 15, l4 = lane >> 4;
  const bf16* Abh = Xh + (size_t)b * NN * C;
  const bf16* Abl = Xl + (size_t)b * NN * C;
  f32x4 acc = {0.f, 0.f, 0.f, 0.f};
#pragma unroll
  for (int ks = 0; ks < 8; ++ks) {
    int ko = ks * 4 + l4;
    short8 a_h = ldg8(Abh + ((size_t)ntile * 32 + ko) * 128 + l15 * 8);
    short8 a_l = ldg8(Abl + ((size_t)ntile * 32 + ko) * 128 + l15 * 8);
    size_t wo = ((size_t)w * 32 + ko) * 128 + l15 * 8;
    short8 w_h = ldg8(Wh + wo);
    short8 w_l = ldg8(Wl + wo);
    acc = mfma16(a_h, w_h, acc);
    acc = mfma16(a_h, w_l, acc);
    acc = mfma16(a_l, w_h, acc);
  }
  float v[4] = {acc[0], acc[1], acc[2], acc[3]};
  size_t tb = ((size_t)ntile * 8 + w * 2) * 128;
  store_tile16(v, Qh + (size_t)b * NN * 64, Ql + (size_t)b * NN * 64, tb,
               scratch[w], lane);
}

// ------- V'[b](c,m) = sum_k W'(c,k) X'[b](m,k) + bias[c]; output swizzled rows=c,K=N ---
__global__ __launch_bounds__(256) void k_gemm_nm(const bf16* __restrict__ Wh,
                                                 const bf16* __restrict__ Wl,
                                                 const bf16* __restrict__ Xh,
                                                 const bf16* __restrict__ Xl,
                                                 const float* __restrict__ bias,
                                                 bf16* __restrict__ Vh,
                                                 bf16* __restrict__ Vl) {
  __shared__ float scratch[4][320];
  int b = blockIdx.z, i0 = blockIdx.x * 64, j0 = blockIdx.y * 64;
  int t = threadIdx.x, lane = t & 63, w = t >> 6;
  int l15 = lane & 15, l4 = lane >> 4;
  const bf16* Xbh = Xh + (size_t)b * NN * C;
  const bf16* Xbl = Xl + (size_t)b * NN * C;
  int ntile = (i0 >> 4) + w;
  f32x4 acc[4];
#pragma unroll
  for (int ct = 0; ct < 4; ++ct) acc[ct] = f32x4{0.f, 0.f, 0.f, 0.f};
#pragma unroll
  for (int ks = 0; ks < 8; ++ks) {
    int ko = ks * 4 + l4;
    short8 a_h = ldg8(Wh + ((size_t)ntile * 32 + ko) * 128 + l15 * 8);
    short8 a_l = ldg8(Wl + ((size_t)ntile * 32 + ko) * 128 + l15 * 8);
#pragma unroll
    for (int ct = 0; ct < 4; ++ct) {
      size_t xo = ((size_t)((j0 >> 4) + ct) * 32 + ko) * 128 + l15 * 8;
      short8 x_h = ldg8(Xbh + xo);
      short8 x_l = ldg8(Xbl + xo);
      acc[ct] = mfma16(a_h, x_h, acc[ct]);
      acc[ct] = mfma16(a_h, x_l, acc[ct]);
      acc[ct] = mfma16(a_l, x_h, acc[ct]);
    }
  }
  float br[4];
#pragma unroll
  for (int r = 0; r < 4; ++r) br[r] = bias[i0 + w * 16 + l4 * 4 + r];
  bf16* Vbh = Vh + (size_t)b * C * NN;
  bf16* Vbl = Vl + (size_t)b * C * NN;
#pragma unroll
  for (int ct = 0; ct < 4; ++ct) {
    float v[4];
#pragma unroll
    for (int r = 0; r < 4; ++r) v[r] = acc[ct][r] + br[r];
    size_t tb = ((size_t)ntile * (NN >> 3) + ((j0 + ct * 16) >> 3)) * 128;
    store_tile16(v, Vbh, Vbl, tb, scratch[w], lane);
  }
}

// ---------------- row softmax stats over E = Q Q^T (split 3-term) ----------------
__global__ __launch_bounds__(256) void k_rowstats(const bf16* __restrict__ Qh,
                                                  const bf16* __restrict__ Ql,
                                                  float* __restrict__ rm,
                                                  float* __restrict__ irs) {
  __shared__ float redM[4][16], redS[4][16];
  int b = blockIdx.y;
  int t = threadIdx.x, lane = t & 63, w = t >> 6;
  int l15 = lane & 15, l4 = lane >> 4;
  int mt = blockIdx.x;
  const bf16* QHb = Qh + (size_t)b * NN * 64;
  const bf16* QLb = Ql + (size_t)b * NN * 64;
  short8 ah0 = ldg8(QHb + ((size_t)mt * 8 + l4) * 128 + l15 * 8);
  short8 ah1 = ldg8(QHb + ((size_t)mt * 8 + 4 + l4) * 128 + l15 * 8);
  short8 al0 = ldg8(QLb + ((size_t)mt * 8 + l4) * 128 + l15 * 8);
  short8 al1 = ldg8(QLb + ((size_t)mt * 8 + 4 + l4) * 128 + l15 * 8);
  float lmax[4], lsum[4];
#pragma unroll
  for (int r = 0; r < 4; ++r) { lmax[r] = -3.4e38f; lsum[r] = 0.f; }
  for (int nb = w * 32; nb < w * 32 + 32; ++nb) {
    short8 bh0 = ldg8(QHb + ((size_t)nb * 8 + l4) * 128 + l15 * 8);
    short8 bh1 = ldg8(QHb + ((size_t)nb * 8 + 4 + l4) * 128 + l15 * 8);
    short8 bl0 = ldg8(QLb + ((size_t)nb * 8 + l4) * 128 + l15 * 8);
    short8 bl1 = ldg8(QLb + ((size_t)nb * 8 + 4 + l4) * 128 + l15 * 8);
    f32x4 e = {0.f, 0.f, 0.f, 0.f};
    e = mfma16(ah0, bh0, e); e = mfma16(ah1, bh1, e);
    e = mfma16(ah0, bl0, e); e = mfma16(ah1, bl1, e);
    e = mfma16(al0, bh0, e); e = mfma16(al1, bh1, e);
#pragma unroll
    for (int r = 0; r < 4; ++r) {
      float v = e[r];
      float nm = fmaxf(lmax[r], v);
      lsum[r] = lsum[r] * __expf(lmax[r] - nm) + __expf(v - nm);
      lmax[r] = nm;
    }
  }
#pragma unroll
  for (int r = 0; r < 4; ++r) {
    for (int mk = 1; mk < 16; mk <<= 1) {
      float om = __shfl_xor(lmax[r], mk, 16);
      float os = __shfl_xor(lsum[r], mk, 16);
      float nm = fmaxf(lmax[r], om);
      lsum[r] = lsum[r] * __expf(lmax[r] - nm) + os * __expf(om - nm);
      lmax[r] = nm;
    }
  }
  if (l15 == 0) {
#pragma unroll
    for (int r = 0; r < 4; ++r) {
      redM[w][l4 * 4 + r] = lmax[r];
      redS[w][l4 * 4 + r] = lsum[r];
    }
  }
  __syncthreads();
  if (t < 16) {
    float m = redM[0][t];
    m = fmaxf(m, redM[1][t]); m = fmaxf(m, redM[2][t]); m = fmaxf(m, redM[3][t]);
    float s = 0.f;
#pragma unroll
    for (int w2 = 0; w2 < 4; ++w2) s += redS[w2][t] * __expf(redM[w2][t] - m);
    rm[b * NN + mt * 16 + t] = m;
    irs[b * NN + mt * 16 + t] = 1.0f / s;
  }
}

// ---------------- fused attention: D' = X - (V att)/(1e-9+colsum), swizzled out ------
// 512 threads / 8 waves per block; block = 64 n-rows x ALL 256 channels.
// Per 32-m step: wave w=(nt,mh) computes ONE 16x16 P tile (P computed once,
// hi-only bf16), all waves then consume P from double-buffered padded LDS for
// their private 32-channel PV slice. One barrier per step.
__global__ __launch_bounds__(512, 4) void k_attnY(const bf16* __restrict__ QH,
                                                  const bf16* __restrict__ QL,
                                                  const bf16* __restrict__ VH,
                                                  const bf16* __restrict__ VL,
                                                  const float* __restrict__ rm,
                                                  const float* __restrict__ irs,
                                                  const float* __restrict__ Xf,
                                                  bf16* __restrict__ DH,
                                                  bf16* __restrict__ DL) {
  __shared__ bf16 Pb[2][16 * 136];   // 16 blocks of 128 + 8 pad
  __shared__ float rmL[2048], irL[2048];
  __shared__ float colLds[64];
  __shared__ float scratch[8][320];
  int b = blockIdx.y, n0 = blockIdx.x * 64;
  int t = threadIdx.x, lane = t & 63, w = t >> 6;
  int l15 = lane & 15, l4 = lane >> 4;
  int nt = w >> 1, mh = w & 1;  // E-tile role
  const bf16* QHb = QH + (size_t)b * NN * 64;
  const bf16* QLb = QL + (size_t)b * NN * 64;
  const bf16* VHb = VH + (size_t)b * C * NN;
  const bf16* VLb = VL + (size_t)b * C * NN;
  // stage rm/irs
  for (int i = t; i < NN; i += 512) {
    rmL[i] = rm[b * NN + i];
    irL[i] = irs[b * NN + i];
  }
  if (t < 64) colLds[t] = 0.f;
  // own Q fragments (rows n0 + nt*16)
  int ntq = (n0 >> 4) + nt;
  short8 qh0 = ldg8(QHb + ((size_t)ntq * 8 + l4) * 128 + l15 * 8);
  short8 qh1 = ldg8(QHb + ((size_t)ntq * 8 + 4 + l4) * 128 + l15 * 8);
  short8 ql0 = ldg8(QLb + ((size_t)ntq * 8 + l4) * 128 + l15 * 8);
  short8 ql1 = ldg8(QLb + ((size_t)ntq * 8 + 4 + l4) * 128 + l15 * 8);
  f32x4 zero = {0.f, 0.f, 0.f, 0.f};
  f32x4 acc[4][2];
#pragma unroll
  for (int n2 = 0; n2 < 4; ++n2)
#pragma unroll
    for (int ct = 0; ct < 2; ++ct) acc[n2][ct] = zero;
  float cac[4] = {0.f, 0.f, 0.f, 0.f};
  __syncthreads();  // rmL/irL ready
  int par = 0;
  for (int s = 0; s < 64; ++s) {
    // ---- E phase: one 16x16 tile (rows nt, m-cols s*32+mh*16) ----
    int mt = s * 2 + mh;
    short8 bh0 = ldg8(QHb + ((size_t)mt * 8 + l4) * 128 + l15 * 8);
    short8 bh1 = ldg8(QHb + ((size_t)mt * 8 + 4 + l4) * 128 + l15 * 8);
    short8 bl0 = ldg8(QLb + ((size_t)mt * 8 + l4) * 128 + l15 * 8);
    short8 bl1 = ldg8(QLb + ((size_t)mt * 8 + 4 + l4) * 128 + l15 * 8);
    f32x4 eA = zero, eB = zero;
    eA = mfma16(qh0, bh0, eA); eB = mfma16(qh1, bh1, eB);
    eA = mfma16(qh0, bl0, eA); eB = mfma16(qh1, bl1, eB);
    eA = mfma16(ql0, bh0, eA); eB = mfma16(ql1, bh1, eB);
    int m = mt * 16 + l15;
    float rmv = rmL[m], iv = irL[m];
    int blk = nt * 4 + mh * 2 + (l15 >> 3);
    bf16* pbw = Pb[par];
#pragma unroll
    for (int r = 0; r < 4; ++r) {
      float p = __expf(eA[r] + eB[r] - rmv) * iv;
      bf16 ph = __float2bfloat16(p);
      cac[r] += __bfloat162float(ph);
      pbw[blk * 136 + (l4 * 4 + r) * 8 + (l15 & 7)] = ph;
    }
    __syncthreads();  // P[par] ready for all
    // ---- PV phase: own 32 channels, k = s*32 ----
    short8 pa[4];
#pragma unroll
    for (int n2 = 0; n2 < 4; ++n2)
      pa[n2] = *reinterpret_cast<const short8*>(&pbw[(n2 * 4 + l4) * 136 + l15 * 8]);
#pragma unroll
    for (int ct = 0; ct < 2; ++ct) {
      int crow = w * 2 + ct;
      short8 vh = ldg8(VHb + ((size_t)crow * 256 + s * 4 + l4) * 128 + l15 * 8);
      short8 vl = ldg8(VLb + ((size_t)crow * 256 + s * 4 + l4) * 128 + l15 * 8);
#pragma unroll
      for (int n2 = 0; n2 < 4; ++n2) {
        acc[n2][ct] = mfma16(pa[n2], vh, acc[n2][ct]);
        acc[n2][ct] = mfma16(pa[n2], vl, acc[n2][ct]);
      }
    }
    par ^= 1;
  }
  // colsum: reduce over 16 m-lanes, combine 2 mh-waves per nt
#pragma unroll
  for (int r = 0; r < 4; ++r) {
    float v2 = cac[r];
    v2 += __shfl_xor(v2, 1, 16); v2 += __shfl_xor(v2, 2, 16);
    v2 += __shfl_xor(v2, 4, 16); v2 += __shfl_xor(v2, 8, 16);
    if (l15 == 0) atomicAdd(&colLds[nt * 16 + l4 * 4 + r], v2);
  }
  __syncthreads();
  if (t < 64) colLds[t] = 1.0f / (1e-9f + colLds[t]);
  __syncthreads();
  bf16* DHb = DH + (size_t)b * NN * C;
  bf16* DLb = DL + (size_t)b * NN * C;
#pragma unroll
  for (int n2 = 0; n2 < 4; ++n2) {
#pragma unroll
    for (int ct = 0; ct < 2; ++ct) {
      float d[4];
      int cidx = w * 32 + ct * 16 + l15;
#pragma unroll
      for (int r = 0; r < 4; ++r) {
        int n = n0 + n2 * 16 + l4 * 4 + r;
        d[r] = Xf[((size_t)(b * NN + n)) * C + cidx] -
               acc[n2][ct][r] * colLds[n2 * 16 + l4 * 4 + r];
      }
      size_t tb = ((size_t)((n0 >> 4) + n2) * 32 + ((w * 32 + ct * 16) >> 3)) * 128;
      store_tile16(d, DHb, DLb, tb, scratch[w], lane);
    }
  }
}

// ---------------- BN finish ----------------
__global__ void k_bnfin(const float* __restrict__ sS, const float* __restrict__ sS2,
                        const float* __restrict__ g, const float* __restrict__ bb,
                        float* __restrict__ scale, float* __restrict__ shift) {
  int c = threadIdx.x;
  float cnt = (float)(BB * NN);
  float mean = sS[c] / cnt;
  float var = fmaxf(sS2[c] / cnt - mean * mean, 0.f);
  float sc = g[c] * rsqrtf(var + 1e-5f);
  scale[c] = sc;
  shift[c] = bb[c] - mean * sc;
}

// ---------------- BN + ReLU (+ residual + out write); X' swizzled out ----------------
template <bool RES>
__global__ __launch_bounds__(256) void k_bnrelu(const float* __restrict__ Tt,
                                                const float* __restrict__ scale,
                                                const float* __restrict__ shift,
                                                float* __restrict__ Xf,
                                                bf16* __restrict__ Xh,
                                                bf16* __restrict__ Xl,
                                                float* __restrict__ outp, int Loff) {
  int row = blockIdx.x;  // b*NN + n
  int c = threadIdx.x;
  size_t idx = (size_t)row * C + c;
  float v = Tt[idx] * scale[c] + shift[c];
  v = fmaxf(v, 0.f);
  if (RES) v += Xf[idx];
  Xf[idx] = v;
  bf16 h, l;
  split2(v, h, l);
  int b = row >> 11;
  int n = row & (NN - 1);
  size_t off = (size_t)b * NN * C +
               ((size_t)(n >> 4) * 32 + (c >> 3)) * 128 + (n & 15) * 8 + (c & 7);
  Xh[off] = h;
  Xl[off] = l;
  if (RES) {
    outp[((size_t)(b * 1024 + Loff + c)) * NN + n] = v;
  }
}

extern "C" void kernel_launch(void* const* d_in, const int* in_sizes, int n_in,
                              void* d_out, int out_size, void* d_ws, size_t ws_size,
                              hipStream_t stream) {
  const float* x       = (const float*)d_in[0];
  const float* conv1_w = (const float*)d_in[1];
  const float* conv2_w = (const float*)d_in[2];
  const float* bn1_g   = (const float*)d_in[3];
  const float* bn1_b   = (const float*)d_in[4];
  const float* bn2_g   = (const float*)d_in[5];
  const float* bn2_b   = (const float*)d_in[6];
  const float* wqk     = (const float*)d_in[7];
  const float* wv      = (const float*)d_in[8];
  const float* bv      = (const float*)d_in[9];
  const float* wt      = (const float*)d_in[10];
  const float* bt      = (const float*)d_in[11];
  const float* sg      = (const float*)d_in[12];
  const float* sb      = (const float*)d_in[13];
  float* out = (float*)d_out;

  char* p = (char*)d_ws;
  auto take = [&](size_t n) { char* r = p; p += n; return r; };
  bf16* WB1h = (bf16*)take(131072);
  bf16* WB1l = (bf16*)take(131072);
  bf16* WB2h = (bf16*)take(131072);
  bf16* WB2l = (bf16*)take(131072);
  bf16* WBQh = (bf16*)take(131072);
  bf16* WBQl = (bf16*)take(131072);
  bf16* WBVh = (bf16*)take(524288);
  bf16* WBVl = (bf16*)take(524288);
  bf16* WBTh = (bf16*)take(524288);
  bf16* WBTl = (bf16*)take(524288);
  bf16* XTh  = (bf16*)take(8388608);
  bf16* XTl  = (bf16*)take(8388608);
  float* XF  = (float*)take(16777216);
  bf16* QTh  = (bf16*)take(2097152);
  bf16* QTl  = (bf16*)take(2097152);
  bf16* VBh  = (bf16*)take(8388608);
  bf16* VBl  = (bf16*)take(8388608);
  float* TT  = (float*)VBh;  // alias: t-GEMM output written after attnY consumed V
  bf16* DTh  = (bf16*)take(8388608);
  bf16* DTl  = (bf16*)take(8388608);
  float* RM   = (float*)take(65536);
  float* IRS  = (float*)take(65536);
  float* STAT = (float*)take(12288);
  float* SCSH = (float*)take(12288);

  hipMemsetAsync(STAT, 0, 6 * 512 * sizeof(float), stream);
  k_cvtW<<<32, 256, 0, stream>>>(conv1_w, WB1h, WB1l, 256);
  k_cvtW<<<32, 256, 0, stream>>>(conv2_w, WB2h, WB2l, 256);
  k_cvtW<<<32, 256, 0, stream>>>(wqk, WBQh, WBQl, 256);
  k_cvtW<<<128, 256, 0, stream>>>(wv, WBVh, WBVl, 1024);
  k_cvtW<<<128, 256, 0, stream>>>(wt, WBTh, WBTl, 1024);
  k_tin<<<dim3(32, 4, 8), 256, 0, stream>>>(x, XTh, XTl);

  // conv1 + bn1 + relu   (TT aliases VB, safe — V not yet used)
  k_gemm_tr<true, false, true><<<dim3(32, 4, 8), 256, 0, stream>>>(
      XTh, XTl, WB1h, WB1l, nullptr, TT, nullptr, nullptr, 256, STAT + 0, STAT + 256);
  k_bnfin<<<1, 256, 0, stream>>>(STAT + 0, STAT + 256, bn1_g, bn1_b, SCSH + 0, SCSH + 256);
  k_bnrelu<false><<<16384, 256, 0, stream>>>(TT, SCSH + 0, SCSH + 256, XF, XTh, XTl, nullptr, 0);

  // conv2 + bn2 + relu
  k_gemm_tr<true, false, true><<<dim3(32, 4, 8), 256, 0, stream>>>(
      XTh, XTl, WB2h, WB2l, nullptr, TT, nullptr, nullptr, 256, STAT + 512, STAT + 768);
  k_bnfin<<<1, 256, 0, stream>>>(STAT + 512, STAT + 768, bn2_g, bn2_b, SCSH + 512, SCSH + 768);
  k_bnrelu<false><<<16384, 256, 0, stream>>>(TT, SCSH + 512, SCSH + 768, XF, XTh, XTl, nullptr, 0);

  for (int L = 0; L < 4; ++L) {
    float* ST = STAT + (2 + L) * 512;
    float* SC = SCSH + (2 + L) * 512;
    // q projection -> Q' swizzled [B], rows=N, K=64
    k_qproj<<<dim3(128, 8), 256, 0, stream>>>(XTh, XTl, WBQh + L * 16384,
                                              WBQl + L * 16384, QTh, QTl);
    // v projection -> V' swizzled [B], rows=C, K=N
    k_gemm_nm<<<dim3(4, 32, 8), 256, 0, stream>>>(WBVh + L * 65536, WBVl + L * 65536,
                                                  XTh, XTl, bv + L * 256, VBh, VBl);
    // softmax row stats
    k_rowstats<<<dim3(128, 8), 256, 0, stream>>>(QTh, QTl, RM, IRS);
    // fused E + softmax (P once) + renorm + V-apply + subtract -> D' swizzled
    k_attnY<<<dim3(32, 8), 512, 0, stream>>>(QTh, QTl, VBh, VBl, RM, IRS, XF, DTh, DTl);
    // t projection + stats (TT aliases VB — V fully consumed by attnY above)
    k_gemm_tr<true, true, true><<<dim3(32, 4, 8), 256, 0, stream>>>(
        DTh, DTl, WBTh + L * 65536, WBTl + L * 65536, bt + L * 256, TT, nullptr, nullptr,
        256, ST, ST + 256);
    k_bnfin<<<1, 256, 0, stream>>>(ST, ST + 256, sg + L * 256, sb + L * 256, SC, SC + 256);
    // bn + relu + residual + output slice
    k_bnrelu<true><<<16384, 256, 0, stream>>>(TT, SC, SC + 256, XF, XTh, XTl, out, L * 256);
  }
}

// Round 7
// 680.359 us; speedup vs baseline: 3.7179x; 1.4307x over previous
//
#include <hip/hip_runtime.h>
#include <hip/hip_bf16.h>

typedef __attribute__((ext_vector_type(8))) short short8;
typedef __attribute__((ext_vector_type(4))) float f32x4;
using bf16 = __hip_bfloat16;

constexpr int C  = 256;
constexpr int BB = 8;
constexpr int NN = 2048;

#define DEVI __device__ __forceinline__

DEVI short8 ldg8(const bf16* p) { return *reinterpret_cast<const short8*>(p); }

DEVI f32x4 mfma16(short8 a, short8 b, f32x4 c) {
  return __builtin_amdgcn_mfma_f32_16x16x32_bf16(a, b, c, 0, 0, 0);
}

DEVI void split2(float x, bf16& h, bf16& l) {
  h = __float2bfloat16(x);
  l = __float2bfloat16(x - __bfloat162float(h));
}

DEVI short b2s(bf16 x) { short s; __builtin_memcpy(&s, &x, 2); return s; }

// Universal fragment-swizzled layout: FR(n,k,K) = ((n>>4)*(K>>3) + (k>>3))*128
// + (n&15)*8 + (k&7).  MFMA fragment load = 1KB contiguous per wave.

DEVI void store_tile16(const float v[4], bf16* __restrict__ H, bf16* __restrict__ L,
                       size_t tilebase, float* lds, int lane) {
  int l15 = lane & 15, l4 = lane >> 4;
#pragma unroll
  for (int r = 0; r < 4; ++r) lds[(l4 * 4 + r) * 20 + l15] = v[r];
  asm volatile("s_waitcnt lgkmcnt(0)" ::: "memory");
  __builtin_amdgcn_sched_barrier(0);
  int n = lane & 15, cg = (lane >> 4) & 1, pl = lane >> 5;
  short8 o;
#pragma unroll
  for (int j = 0; j < 8; ++j) {
    bf16 h, l;
    split2(lds[n * 20 + cg * 8 + j], h, l);
    o[j] = pl ? b2s(l) : b2s(h);
  }
  bf16* P = pl ? L : H;
  *reinterpret_cast<short8*>(P + tilebase + (size_t)cg * 128 + n * 8) = o;
}

// ---------------- weights fp32 [rows][256] -> swizzled bf16 hi/lo ----------------
__global__ __launch_bounds__(256) void k_cvtW(const float* __restrict__ s,
                                              bf16* __restrict__ dh,
                                              bf16* __restrict__ dl, int rows) {
  int idx = blockIdx.x * 256 + threadIdx.x;
  if (idx >= rows * 32) return;
  int row = idx >> 5, kg = idx & 31;
  const float* sp = s + row * 256 + kg * 8;
  short8 oh, ol;
#pragma unroll
  for (int j = 0; j < 8; ++j) {
    bf16 h, l;
    split2(sp[j], h, l);
    oh[j] = b2s(h); ol[j] = b2s(l);
  }
  size_t off = ((size_t)(row >> 4) * 32 + kg) * 128 + (row & 15) * 8;
  *reinterpret_cast<short8*>(dh + off) = oh;
  *reinterpret_cast<short8*>(dl + off) = ol;
}

// ---------------- x [B][C][N] f32 -> X' swizzled (rows=n, K=256) hi/lo ----------------
__global__ __launch_bounds__(256) void k_tin(const float* __restrict__ x,
                                             bf16* __restrict__ Xh,
                                             bf16* __restrict__ Xl) {
  __shared__ float tile[64][65];
  int b = blockIdx.z, n0 = blockIdx.x * 64, c0 = blockIdx.y * 64;
  int t = threadIdx.x;
  int tn = t & 63, tq = t >> 6;
#pragma unroll
  for (int i = 0; i < 16; ++i) {
    int cc = i * 4 + tq;
    tile[cc][tn] = x[((size_t)(b * C + c0 + cc)) * NN + n0 + tn];
  }
  __syncthreads();
  bf16* XHb = Xh + (size_t)b * NN * C;
  bf16* XLb = Xl + (size_t)b * NN * C;
#pragma unroll
  for (int i = 0; i < 4; ++i) {
    int e = i * 256 + t;
    int nl = e & 63;
    int cgp = e >> 6;
    int cg = cgp & 7, pl = cgp >> 3;
    short8 o;
#pragma unroll
    for (int j = 0; j < 8; ++j) {
      bf16 h, l;
      split2(tile[cg * 8 + j][nl], h, l);
      o[j] = pl ? b2s(l) : b2s(h);
    }
    int n = n0 + nl;
    size_t off = ((size_t)(n >> 4) * 32 + ((c0 >> 3) + cg)) * 128 + (n & 15) * 8;
    bf16* P = pl ? XLb : XHb;
    *reinterpret_cast<short8*>(P + off) = o;
  }
}

// ------- GEMM: Out[b][n][o] = sum_k A'[b](n,k) W'(o,k) (+bias[o]); A',W' swizzled ------
// Grid: (B, n-tiles/4, o-tiles/4) -> batch fastest for XCD-L2 affinity.
template <bool OUTF32, bool BIASJ, bool STATS>
__global__ __launch_bounds__(256) void k_gemm_tr(const bf16* __restrict__ Ah,
                                                 const bf16* __restrict__ Al,
                                                 const bf16* __restrict__ Wh,
                                                 const bf16* __restrict__ Wl,
                                                 const float* __restrict__ bias,
                                                 float* __restrict__ OutF,
                                                 bf16* __restrict__ Oh,
                                                 bf16* __restrict__ Ol, int OD,
                                                 float* __restrict__ sS,
                                                 float* __restrict__ sS2) {
  __shared__ float smS[64], smS2[64];
  __shared__ float scratch[4][320];
  int b = blockIdx.x, i0 = blockIdx.y * 64, j0 = blockIdx.z * 64;
  int t = threadIdx.x, lane = t & 63, w = t >> 6;
  int l15 = lane & 15, l4 = lane >> 4;
  if (STATS) {
    if (t < 64) { smS[t] = 0.f; smS2[t] = 0.f; }
    __syncthreads();
  }
  const bf16* Abh = Ah + (size_t)b * NN * C;
  const bf16* Abl = Al + (size_t)b * NN * C;
  int ntile = (i0 >> 4) + w;
  f32x4 acc[4];
#pragma unroll
  for (int ct = 0; ct < 4; ++ct) acc[ct] = f32x4{0.f, 0.f, 0.f, 0.f};
#pragma unroll
  for (int ks = 0; ks < 8; ++ks) {
    int ko = ks * 4 + l4;
    short8 a_h = ldg8(Abh + ((size_t)ntile * 32 + ko) * 128 + l15 * 8);
    short8 a_l = ldg8(Abl + ((size_t)ntile * 32 + ko) * 128 + l15 * 8);
#pragma unroll
    for (int ct = 0; ct < 4; ++ct) {
      size_t wo = ((size_t)((j0 >> 4) + ct) * 32 + ko) * 128 + l15 * 8;
      short8 w_h = ldg8(Wh + wo);
      short8 w_l = ldg8(Wl + wo);
      acc[ct] = mfma16(a_h, w_h, acc[ct]);
      acc[ct] = mfma16(a_h, w_l, acc[ct]);
      acc[ct] = mfma16(a_l, w_h, acc[ct]);
    }
  }
#pragma unroll
  for (int ct = 0; ct < 4; ++ct) {
    float bj = 0.f;
    if (BIASJ) bj = bias[j0 + ct * 16 + l15];
    float v[4];
    float s = 0.f, s2 = 0.f;
#pragma unroll
    for (int r = 0; r < 4; ++r) {
      v[r] = acc[ct][r] + bj;
      if (STATS) { s += v[r]; s2 += v[r] * v[r]; }
    }
    if (OUTF32) {
#pragma unroll
      for (int r = 0; r < 4; ++r) {
        int row = i0 + w * 16 + l4 * 4 + r;
        OutF[((size_t)(b * NN + row)) * OD + j0 + ct * 16 + l15] = v[r];
      }
    } else {
      bf16* Obh = Oh + (size_t)b * NN * OD;
      bf16* Obl = Ol + (size_t)b * NN * OD;
      size_t tb = ((size_t)ntile * (OD >> 3) + ((j0 + ct * 16) >> 3)) * 128;
      store_tile16(v, Obh, Obl, tb, scratch[w], lane);
    }
    if (STATS) {
      s += __shfl_xor(s, 16); s2 += __shfl_xor(s2, 16);
      s += __shfl_xor(s, 32); s2 += __shfl_xor(s2, 32);
      if (l4 == 0) {
        atomicAdd(&smS[ct * 16 + l15], s);
        atomicAdd(&smS2[ct * 16 + l15], s2);
      }
    }
  }
  if (STATS) {
    __syncthreads();
    if (t < 64) {
      atomicAdd(&sS[j0 + t], smS[t]);
      atomicAdd(&sS2[j0 + t], smS2[t]);
    }
  }
}

// ------- q-projection: one 16-row tile per block, wave w = 16-col ct tile -----------
__global__ __launch_bounds__(256) void k_qproj(const bf16* __restrict__ Xh,
                                               const bf16* __restrict__ Xl,
                                               const bf16* __restrict__ Wh,
                                               const bf16* __restrict__ Wl,
                                               bf16* __restrict__ Qh,
                                               bf16* __restrict__ Ql) {
  __shared__ float scratch[4][320];
  int b = blockIdx.x, ntile = blockIdx.y;
  int t = threadIdx.x, lane = t & 63, w = t >> 6;
  int l15 = lane & 15, l4 = lane >> 4;
  const bf16* Abh = Xh + (size_t)b * NN * C;
  const bf16* Abl = Xl + (size_t)b * NN * C;
  f32x4 acc = {0.f, 0.f, 0.f, 0.f};
#pragma unroll
  for (int ks = 0; ks < 8; ++ks) {
    int ko = ks * 4 + l4;
    short8 a_h = ldg8(Abh + ((size_t)ntile * 32 + ko) * 128 + l15 * 8);
    short8 a_l = ldg8(Abl + ((size_t)ntile * 32 + ko) * 128 + l15 * 8);
    size_t wo = ((size_t)w * 32 + ko) * 128 + l15 * 8;
    short8 w_h = ldg8(Wh + wo);
    short8 w_l = ldg8(Wl + wo);
    acc = mfma16(a_h, w_h, acc);
    acc = mfma16(a_h, w_l, acc);
    acc = mfma16(a_l, w_h, acc);
  }
  float v[4] = {acc[0], acc[1], acc[2], acc[3]};
  size_t tb = ((size_t)ntile * 8 + w * 2) * 128;
  store_tile16(v, Qh + (size_t)b * NN * 64, Ql + (size_t)b * NN * 64, tb,
               scratch[w], lane);
}

// ------- V'[b](c,m) = sum_k W'(c,k) X'[b](m,k) + bias[c]; output swizzled rows=c,K=N ---
__global__ __launch_bounds__(256) void k_gemm_nm(const bf16* __restrict__ Wh,
                                                 const bf16* __restrict__ Wl,
                                                 const bf16* __restrict__ Xh,
                                                 const bf16* __restrict__ Xl,
                                                 const float* __restrict__ bias,
                                                 bf16* __restrict__ Vh,
                                                 bf16* __restrict__ Vl) {
  __shared__ float scratch[4][320];
  int b = blockIdx.x, i0 = blockIdx.y * 64, j0 = blockIdx.z * 64;
  int t = threadIdx.x, lane = t & 63, w = t >> 6;
  int l15 = lane & 15, l4 = lane >> 4;
  const bf16* Xbh = Xh + (size_t)b * NN * C;
  const bf16* Xbl = Xl + (size_t)b * NN * C;
  int ntile = (i0 >> 4) + w;
  f32x4 acc[4];
#pragma unroll
  for (int ct = 0; ct < 4; ++ct) acc[ct] = f32x4{0.f, 0.f, 0.f, 0.f};
#pragma unroll
  for (int ks = 0; ks < 8; ++ks) {
    int ko = ks * 4 + l4;
    short8 a_h = ldg8(Wh + ((size_t)ntile * 32 + ko) * 128 + l15 * 8);
    short8 a_l = ldg8(Wl + ((size_t)ntile * 32 + ko) * 128 + l15 * 8);
#pragma unroll
    for (int ct = 0; ct < 4; ++ct) {
      size_t xo = ((size_t)((j0 >> 4) + ct) * 32 + ko) * 128 + l15 * 8;
      short8 x_h = ldg8(Xbh + xo);
      short8 x_l = ldg8(Xbl + xo);
      acc[ct] = mfma16(a_h, x_h, acc[ct]);
      acc[ct] = mfma16(a_h, x_l, acc[ct]);
      acc[ct] = mfma16(a_l, x_h, acc[ct]);
    }
  }
  float br[4];
#pragma unroll
  for (int r = 0; r < 4; ++r) br[r] = bias[i0 + w * 16 + l4 * 4 + r];
  bf16* Vbh = Vh + (size_t)b * C * NN;
  bf16* Vbl = Vl + (size_t)b * C * NN;
#pragma unroll
  for (int ct = 0; ct < 4; ++ct) {
    float v[4];
#pragma unroll
    for (int r = 0; r < 4; ++r) v[r] = acc[ct][r] + br[r];
    size_t tb = ((size_t)ntile * (NN >> 3) + ((j0 + ct * 16) >> 3)) * 128;
    store_tile16(v, Vbh, Vbl, tb, scratch[w], lane);
  }
}

// ---------------- row softmax stats over E = Q Q^T (split 3-term) ----------------
__global__ __launch_bounds__(256) void k_rowstats(const bf16* __restrict__ Qh,
                                                  const bf16* __restrict__ Ql,
                                                  float* __restrict__ rm,
                                                  float* __restrict__ irs) {
  __shared__ float redM[4][16], redS[4][16];
  int b = blockIdx.x;
  int t = threadIdx.x, lane = t & 63, w = t >> 6;
  int l15 = lane & 15, l4 = lane >> 4;
  int mt = blockIdx.y;
  const bf16* QHb = Qh + (size_t)b * NN * 64;
  const bf16* QLb = Ql + (size_t)b * NN * 64;
  short8 ah0 = ldg8(QHb + ((size_t)mt * 8 + l4) * 128 + l15 * 8);
  short8 ah1 = ldg8(QHb + ((size_t)mt * 8 + 4 + l4) * 128 + l15 * 8);
  short8 al0 = ldg8(QLb + ((size_t)mt * 8 + l4) * 128 + l15 * 8);
  short8 al1 = ldg8(QLb + ((size_t)mt * 8 + 4 + l4) * 128 + l15 * 8);
  float lmax[4], lsum[4];
#pragma unroll
  for (int r = 0; r < 4; ++r) { lmax[r] = -3.4e38f; lsum[r] = 0.f; }
  for (int nb = w * 32; nb < w * 32 + 32; ++nb) {
    short8 bh0 = ldg8(QHb + ((size_t)nb * 8 + l4) * 128 + l15 * 8);
    short8 bh1 = ldg8(QHb + ((size_t)nb * 8 + 4 + l4) * 128 + l15 * 8);
    short8 bl0 = ldg8(QLb + ((size_t)nb * 8 + l4) * 128 + l15 * 8);
    short8 bl1 = ldg8(QLb + ((size_t)nb * 8 + 4 + l4) * 128 + l15 * 8);
    f32x4 e = {0.f, 0.f, 0.f, 0.f};
    e = mfma16(ah0, bh0, e); e = mfma16(ah1, bh1, e);
    e = mfma16(ah0, bl0, e); e = mfma16(ah1, bl1, e);
    e = mfma16(al0, bh0, e); e = mfma16(al1, bh1, e);
#pragma unroll
    for (int r = 0; r < 4; ++r) {
      float v = e[r];
      float nm = fmaxf(lmax[r], v);
      lsum[r] = lsum[r] * __expf(lmax[r] - nm) + __expf(v - nm);
      lmax[r] = nm;
    }
  }
#pragma unroll
  for (int r = 0; r < 4; ++r) {
    for (int mk = 1; mk < 16; mk <<= 1) {
      float om = __shfl_xor(lmax[r], mk, 16);
      float os = __shfl_xor(lsum[r], mk, 16);
      float nm = fmaxf(lmax[r], om);
      lsum[r] = lsum[r] * __expf(lmax[r] - nm) + os * __expf(om - nm);
      lmax[r] = nm;
    }
  }
  if (l15 == 0) {
#pragma unroll
    for (int r = 0; r < 4; ++r) {
      redM[w][l4 * 4 + r] = lmax[r];
      redS[w][l4 * 4 + r] = lsum[r];
    }
  }
  __syncthreads();
  if (t < 16) {
    float m = redM[0][t];
    m = fmaxf(m, redM[1][t]); m = fmaxf(m, redM[2][t]); m = fmaxf(m, redM[3][t]);
    float s = 0.f;
#pragma unroll
    for (int w2 = 0; w2 < 4; ++w2) s += redS[w2][t] * __expf(redM[w2][t] - m);
    rm[b * NN + mt * 16 + t] = m;
    irs[b * NN + mt * 16 + t] = 1.0f / s;
  }
}

// ---------------- fused attention: D' = X - (V att)/(1e-9+colsum), swizzled out ------
// 1D grid 512, bid&7 = batch (XCD-pinned). Block: 32 n-rows x 256 ch, 8 waves.
// Per 128-m step: wave (nt=w>>2, p=w&3) computes two 16x16 P tiles (P once,
// hi-only); raw s_barrier with lgkmcnt-only drain (V prefetch stays in flight);
// each wave then does PV for its private 32 channels. 16 barriers total.
__global__ __launch_bounds__(512, 4) void k_attnY(const bf16* __restrict__ QH,
                                                  const bf16* __restrict__ QL,
                                                  const bf16* __restrict__ VH,
                                                  const bf16* __restrict__ VL,
                                                  const float* __restrict__ rm,
                                                  const float* __restrict__ irs,
                                                  const float* __restrict__ Xf,
                                                  bf16* __restrict__ DH,
                                                  bf16* __restrict__ DL) {
  __shared__ bf16 Pb[2][32 * 136];
  __shared__ float rmL[2048], irL[2048];
  __shared__ float colLds[32];
  __shared__ float scratch[8][320];
  int bid = blockIdx.x;
  int b = bid & 7, n0 = (bid >> 3) * 32;
  int t = threadIdx.x, lane = t & 63, w = t >> 6;
  int l15 = lane & 15, l4 = lane >> 4;
  int nt = w >> 2, pp = w & 3;
  const bf16* QHb = QH + (size_t)b * NN * 64;
  const bf16* QLb = QL + (size_t)b * NN * 64;
  const bf16* VHb = VH + (size_t)b * C * NN;
  const bf16* VLb = VL + (size_t)b * C * NN;
  for (int i = t; i < NN; i += 512) {
    rmL[i] = rm[b * NN + i];
    irL[i] = irs[b * NN + i];
  }
  if (t < 32) colLds[t] = 0.f;
  int ntq = (n0 >> 4) + nt;
  short8 qh0 = ldg8(QHb + ((size_t)ntq * 8 + l4) * 128 + l15 * 8);
  short8 qh1 = ldg8(QHb + ((size_t)ntq * 8 + 4 + l4) * 128 + l15 * 8);
  short8 ql0 = ldg8(QLb + ((size_t)ntq * 8 + l4) * 128 + l15 * 8);
  short8 ql1 = ldg8(QLb + ((size_t)ntq * 8 + 4 + l4) * 128 + l15 * 8);
  f32x4 zero = {0.f, 0.f, 0.f, 0.f};
  f32x4 acc[2][2];
#pragma unroll
  for (int a = 0; a < 2; ++a)
#pragma unroll
    for (int ct = 0; ct < 2; ++ct) acc[a][ct] = zero;
  float cac[4] = {0.f, 0.f, 0.f, 0.f};
  __syncthreads();
  for (int s = 0; s < 16; ++s) {
    bf16* pbw = Pb[s & 1];
    // ---- E phase: two 16x16 tiles ----
#pragma unroll
    for (int sub = 0; sub < 2; ++sub) {
      int mt8 = pp * 2 + sub;
      int gmt = s * 8 + mt8;
      short8 bh0 = ldg8(QHb + ((size_t)gmt * 8 + l4) * 128 + l15 * 8);
      short8 bh1 = ldg8(QHb + ((size_t)gmt * 8 + 4 + l4) * 128 + l15 * 8);
      short8 bl0 = ldg8(QLb + ((size_t)gmt * 8 + l4) * 128 + l15 * 8);
      short8 bl1 = ldg8(QLb + ((size_t)gmt * 8 + 4 + l4) * 128 + l15 * 8);
      f32x4 eA = zero, eB = zero;
      eA = mfma16(qh0, bh0, eA); eB = mfma16(qh1, bh1, eB);
      eA = mfma16(qh0, bl0, eA); eB = mfma16(qh1, bl1, eB);
      eA = mfma16(ql0, bh0, eA); eB = mfma16(ql1, bh1, eB);
      float rmv = rmL[gmt * 16 + l15], iv = irL[gmt * 16 + l15];
      int blk = nt * 16 + mt8 * 2 + (l15 >> 3);
#pragma unroll
      for (int r = 0; r < 4; ++r) {
        float p = __expf(eA[r] + eB[r] - rmv) * iv;
        bf16 ph = __float2bfloat16(p);
        cac[r] += __bfloat162float(ph);
        pbw[blk * 136 + (l4 * 4 + r) * 8 + (l15 & 7)] = ph;
      }
    }
    // ---- prefetch V kc 0,1 (stays in flight across raw barrier) ----
    short8 vhA[2][2], vlA[2][2];
#pragma unroll
    for (int kc = 0; kc < 2; ++kc)
#pragma unroll
      for (int ct = 0; ct < 2; ++ct) {
        size_t vo = ((size_t)(w * 2 + ct) * 256 + s * 16 + kc * 4 + l4) * 128 + l15 * 8;
        vhA[kc][ct] = ldg8(VHb + vo);
        vlA[kc][ct] = ldg8(VLb + vo);
      }
    asm volatile("s_waitcnt lgkmcnt(0)" ::: "memory");
    __builtin_amdgcn_sched_barrier(0);
    __builtin_amdgcn_s_barrier();
    // ---- issue V kc 2,3, then PV ----
    short8 vhB[2][2], vlB[2][2];
#pragma unroll
    for (int kc = 0; kc < 2; ++kc)
#pragma unroll
      for (int ct = 0; ct < 2; ++ct) {
        size_t vo = ((size_t)(w * 2 + ct) * 256 + s * 16 + (kc + 2) * 4 + l4) * 128 + l15 * 8;
        vhB[kc][ct] = ldg8(VHb + vo);
        vlB[kc][ct] = ldg8(VLb + vo);
      }
#pragma unroll
    for (int kc = 0; kc < 2; ++kc) {
      short8 pa0 = *reinterpret_cast<const short8*>(&pbw[(kc * 4 + l4) * 136 + l15 * 8]);
      short8 pa1 = *reinterpret_cast<const short8*>(&pbw[(16 + kc * 4 + l4) * 136 + l15 * 8]);
#pragma unroll
      for (int ct = 0; ct < 2; ++ct) {
        acc[0][ct] = mfma16(pa0, vhA[kc][ct], acc[0][ct]);
        acc[0][ct] = mfma16(pa0, vlA[kc][ct], acc[0][ct]);
        acc[1][ct] = mfma16(pa1, vhA[kc][ct], acc[1][ct]);
        acc[1][ct] = mfma16(pa1, vlA[kc][ct], acc[1][ct]);
      }
    }
#pragma unroll
    for (int kc = 0; kc < 2; ++kc) {
      short8 pa0 = *reinterpret_cast<const short8*>(&pbw[((kc + 2) * 4 + l4) * 136 + l15 * 8]);
      short8 pa1 = *reinterpret_cast<const short8*>(&pbw[(16 + (kc + 2) * 4 + l4) * 136 + l15 * 8]);
#pragma unroll
      for (int ct = 0; ct < 2; ++ct) {
        acc[0][ct] = mfma16(pa0, vhB[kc][ct], acc[0][ct]);
        acc[0][ct] = mfma16(pa0, vlB[kc][ct], acc[0][ct]);
        acc[1][ct] = mfma16(pa1, vhB[kc][ct], acc[1][ct]);
        acc[1][ct] = mfma16(pa1, vlB[kc][ct], acc[1][ct]);
      }
    }
  }
  // colsum: reduce over 16 m-lanes; 4 p-waves per nt combine via LDS atomics
#pragma unroll
  for (int r = 0; r < 4; ++r) {
    float v2 = cac[r];
    v2 += __shfl_xor(v2, 1, 16); v2 += __shfl_xor(v2, 2, 16);
    v2 += __shfl_xor(v2, 4, 16); v2 += __shfl_xor(v2, 8, 16);
    if (l15 == 0) atomicAdd(&colLds[nt * 16 + l4 * 4 + r], v2);
  }
  __syncthreads();
  if (t < 32) colLds[t] = 1.0f / (1e-9f + colLds[t]);
  __syncthreads();
  bf16* DHb = DH + (size_t)b * NN * C;
  bf16* DLb = DL + (size_t)b * NN * C;
#pragma unroll
  for (int a = 0; a < 2; ++a) {
#pragma unroll
    for (int ct = 0; ct < 2; ++ct) {
      float d[4];
      int cidx = w * 32 + ct * 16 + l15;
#pragma unroll
      for (int r = 0; r < 4; ++r) {
        int n = n0 + a * 16 + l4 * 4 + r;
        d[r] = Xf[((size_t)(b * NN + n)) * C + cidx] -
               acc[a][ct][r] * colLds[a * 16 + l4 * 4 + r];
      }
      size_t tb = ((size_t)((n0 >> 4) + a) * 32 + ((w * 32 + ct * 16) >> 3)) * 128;
      store_tile16(d, DHb, DLb, tb, scratch[w], lane);
    }
  }
}

// ---------------- BN finish ----------------
__global__ void k_bnfin(const float* __restrict__ sS, const float* __restrict__ sS2,
                        const float* __restrict__ g, const float* __restrict__ bb,
                        float* __restrict__ scale, float* __restrict__ shift) {
  int c = threadIdx.x;
  float cnt = (float)(BB * NN);
  float mean = sS[c] / cnt;
  float var = fmaxf(sS2[c] / cnt - mean * mean, 0.f);
  float sc = g[c] * rsqrtf(var + 1e-5f);
  scale[c] = sc;
  shift[c] = bb[c] - mean * sc;
}

// ---------------- BN + ReLU (+ residual + out via LDS transpose) ----------------
// Block: 16 n-rows x 256 c; out store coalesced along n.
template <bool RES>
__global__ __launch_bounds__(256) void k_bnrelu(const float* __restrict__ Tt,
                                                const float* __restrict__ scale,
                                                const float* __restrict__ shift,
                                                float* __restrict__ Xf,
                                                bf16* __restrict__ Xh,
                                                bf16* __restrict__ Xl,
                                                float* __restrict__ outp, int Loff) {
  __shared__ float vb[16][257];
  int b = blockIdx.x, n0 = blockIdx.y * 16;
  int c = threadIdx.x;
  float sc = scale[c], sh = shift[c];
#pragma unroll
  for (int i = 0; i < 16; ++i) {
    int n = n0 + i;
    size_t idx = ((size_t)(b * NN + n)) * C + c;
    float v = Tt[idx] * sc + sh;
    v = fmaxf(v, 0.f);
    if (RES) v += Xf[idx];
    Xf[idx] = v;
    bf16 h, l;
    split2(v, h, l);
    size_t off = (size_t)b * NN * C +
                 ((size_t)(n >> 4) * 32 + (c >> 3)) * 128 + (n & 15) * 8 + (c & 7);
    Xh[off] = h;
    Xl[off] = l;
    if (RES) vb[i][c] = v;
  }
  if (RES) {
    __syncthreads();
    int nl = threadIdx.x & 15, cb = threadIdx.x >> 4;
#pragma unroll
    for (int j = 0; j < 16; ++j) {
      int cc = cb + j * 16;
      outp[((size_t)(b * 1024 + Loff + cc)) * NN + n0 + nl] = vb[nl][cc];
    }
  }
}

extern "C" void kernel_launch(void* const* d_in, const int* in_sizes, int n_in,
                              void* d_out, int out_size, void* d_ws, size_t ws_size,
                              hipStream_t stream) {
  const float* x       = (const float*)d_in[0];
  const float* conv1_w = (const float*)d_in[1];
  const float* conv2_w = (const float*)d_in[2];
  const float* bn1_g   = (const float*)d_in[3];
  const float* bn1_b   = (const float*)d_in[4];
  const float* bn2_g   = (const float*)d_in[5];
  const float* bn2_b   = (const float*)d_in[6];
  const float* wqk     = (const float*)d_in[7];
  const float* wv      = (const float*)d_in[8];
  const float* bv      = (const float*)d_in[9];
  const float* wt      = (const float*)d_in[10];
  const float* bt      = (const float*)d_in[11];
  const float* sg      = (const float*)d_in[12];
  const float* sb      = (const float*)d_in[13];
  float* out = (float*)d_out;

  char* p = (char*)d_ws;
  auto take = [&](size_t n) { char* r = p; p += n; return r; };
  bf16* WB1h = (bf16*)take(131072);
  bf16* WB1l = (bf16*)take(131072);
  bf16* WB2h = (bf16*)take(131072);
  bf16* WB2l = (bf16*)take(131072);
  bf16* WBQh = (bf16*)take(131072);
  bf16* WBQl = (bf16*)take(131072);
  bf16* WBVh = (bf16*)take(524288);
  bf16* WBVl = (bf16*)take(524288);
  bf16* WBTh = (bf16*)take(524288);
  bf16* WBTl = (bf16*)take(524288);
  bf16* XTh  = (bf16*)take(8388608);
  bf16* XTl  = (bf16*)take(8388608);
  float* XF  = (float*)take(16777216);
  bf16* QTh  = (bf16*)take(2097152);
  bf16* QTl  = (bf16*)take(2097152);
  bf16* VBh  = (bf16*)take(8388608);
  bf16* VBl  = (bf16*)take(8388608);
  float* TT  = (float*)VBh;  // alias: t-GEMM output written after attnY consumed V
  bf16* DTh  = (bf16*)take(8388608);
  bf16* DTl  = (bf16*)take(8388608);
  float* RM   = (float*)take(65536);
  float* IRS  = (float*)take(65536);
  float* STAT = (float*)take(12288);
  float* SCSH = (float*)take(12288);

  hipMemsetAsync(STAT, 0, 6 * 512 * sizeof(float), stream);
  k_cvtW<<<32, 256, 0, stream>>>(conv1_w, WB1h, WB1l, 256);
  k_cvtW<<<32, 256, 0, stream>>>(conv2_w, WB2h, WB2l, 256);
  k_cvtW<<<32, 256, 0, stream>>>(wqk, WBQh, WBQl, 256);
  k_cvtW<<<128, 256, 0, stream>>>(wv, WBVh, WBVl, 1024);
  k_cvtW<<<128, 256, 0, stream>>>(wt, WBTh, WBTl, 1024);
  k_tin<<<dim3(32, 4, 8), 256, 0, stream>>>(x, XTh, XTl);

  // conv1 + bn1 + relu   (TT aliases VB, safe — V not yet used)
  k_gemm_tr<true, false, true><<<dim3(8, 32, 4), 256, 0, stream>>>(
      XTh, XTl, WB1h, WB1l, nullptr, TT, nullptr, nullptr, 256, STAT + 0, STAT + 256);
  k_bnfin<<<1, 256, 0, stream>>>(STAT + 0, STAT + 256, bn1_g, bn1_b, SCSH + 0, SCSH + 256);
  k_bnrelu<false><<<dim3(8, 128), 256, 0, stream>>>(TT, SCSH + 0, SCSH + 256, XF, XTh, XTl,
                                                    nullptr, 0);

  // conv2 + bn2 + relu
  k_gemm_tr<true, false, true><<<dim3(8, 32, 4), 256, 0, stream>>>(
      XTh, XTl, WB2h, WB2l, nullptr, TT, nullptr, nullptr, 256, STAT + 512, STAT + 768);
  k_bnfin<<<1, 256, 0, stream>>>(STAT + 512, STAT + 768, bn2_g, bn2_b, SCSH + 512, SCSH + 768);
  k_bnrelu<false><<<dim3(8, 128), 256, 0, stream>>>(TT, SCSH + 512, SCSH + 768, XF, XTh, XTl,
                                                    nullptr, 0);

  for (int L = 0; L < 4; ++L) {
    float* ST = STAT + (2 + L) * 512;
    float* SC = SCSH + (2 + L) * 512;
    // q projection -> Q' swizzled [B], rows=N, K=64
    k_qproj<<<dim3(8, 128), 256, 0, stream>>>(XTh, XTl, WBQh + L * 16384,
                                              WBQl + L * 16384, QTh, QTl);
    // v projection -> V' swizzled [B], rows=C, K=N
    k_gemm_nm<<<dim3(8, 4, 32), 256, 0, stream>>>(WBVh + L * 65536, WBVl + L * 65536,
                                                  XTh, XTl, bv + L * 256, VBh, VBl);
    // softmax row stats
    k_rowstats<<<dim3(8, 128), 256, 0, stream>>>(QTh, QTl, RM, IRS);
    // fused E + softmax (P once) + renorm + V-apply + subtract -> D' swizzled
    k_attnY<<<512, 512, 0, stream>>>(QTh, QTl, VBh, VBl, RM, IRS, XF, DTh, DTl);
    // t projection + stats (TT aliases VB — V fully consumed by attnY above)
    k_gemm_tr<true, true, true><<<dim3(8, 32, 4), 256, 0, stream>>>(
        DTh, DTl, WBTh + L * 65536, WBTl + L * 65536, bt + L * 256, TT, nullptr, nullptr,
        256, ST, ST + 256);
    k_bnfin<<<1, 256, 0, stream>>>(ST, ST + 256, sg + L * 256, sb + L * 256, SC, SC + 256);
    // bn + relu + residual + output slice
    k_bnrelu<true><<<dim3(8, 128), 256, 0, stream>>>(TT, SC, SC + 256, XF, XTh, XTl, out,
                                                     L * 256);
  }
}